// Round 1
// baseline (552.158 us; speedup 1.0000x reference)
//
#include <hip/hip_runtime.h>

typedef __bf16 bf16x8 __attribute__((ext_vector_type(8)));
typedef float f32x4 __attribute__((ext_vector_type(4)));
typedef unsigned int u32x4 __attribute__((ext_vector_type(4)));

#define EMB 2048
#define NH 16
#define HD 128
#define TSEQ 4096

// ---------- helpers ----------
__device__ __forceinline__ unsigned short f2bf(float x) {
  unsigned int u = __builtin_bit_cast(unsigned int, x);
  u += 0x7fffu + ((u >> 16) & 1u);   // RNE
  return (unsigned short)(u >> 16);
}

__device__ __forceinline__ void gl_lds16(const void* g, void* l) {
  __builtin_amdgcn_global_load_lds((__attribute__((address_space(1))) void*)(void*)g,
                                   (__attribute__((address_space(3))) void*)l, 16, 0, 0);
}

template <typename OutT>
__device__ __forceinline__ void store_out(OutT* p, float v) {
  if constexpr (sizeof(OutT) == 2) { *p = f2bf(v); } else { *p = v; }
}

// ---------- fp32 -> bf16 convert (vectorized 8/thread) ----------
__global__ __launch_bounds__(256) void cvt_kernel(const float* __restrict__ in,
                                                  unsigned short* __restrict__ outp, int n8) {
  int i = blockIdx.x * 256 + threadIdx.x;
  if (i >= n8) return;
  const float4* p = (const float4*)in + (size_t)i * 2;
  float4 a = p[0], b = p[1];
  u32x4 r;
  r.x = (unsigned)f2bf(a.x) | ((unsigned)f2bf(a.y) << 16);
  r.y = (unsigned)f2bf(a.z) | ((unsigned)f2bf(a.w) << 16);
  r.z = (unsigned)f2bf(b.x) | ((unsigned)f2bf(b.y) << 16);
  r.w = (unsigned)f2bf(b.z) | ((unsigned)f2bf(b.w) << 16);
  ((u32x4*)outp)[i] = r;
}

// ---------- NT GEMM: C[M,N] = A[M,K] * B[N,K]^T   (bf16 in, OutT out) ----------
// 128x128 tile, BK=32, 4 waves (2x2 of 64x64), global_load_lds width-16 staging.
template <typename OutT>
__global__ __launch_bounds__(256) void gemm_nt(const unsigned short* __restrict__ A,
                                               const unsigned short* __restrict__ B,
                                               OutT* __restrict__ C, int M, int N, int K) {
  __shared__ char smem[16384];
  char* sA = smem;
  char* sB = smem + 8192;
  const int t = threadIdx.x;
  const int m0 = blockIdx.y * 128, n0 = blockIdx.x * 128;
  const int l = t & 63, lg = l >> 4, l15 = l & 15;
  const int w = t >> 6, wm = w >> 1, wn = w & 1;

  f32x4 acc[4][4] = {};

  const int rowS = t >> 2;
  const int cbS = (t & 3) * 16;
  const char* Ab = (const char*)A + ((size_t)(m0 + rowS) * K) * 2 + cbS;
  const char* Bb = (const char*)B + ((size_t)(n0 + rowS) * K) * 2 + cbS;
  const size_t rowStep = (size_t)64 * K * 2;

  for (int kt = 0; kt < K; kt += 32) {
    __syncthreads();
    gl_lds16(Ab, sA + t * 16);
    gl_lds16(Ab + rowStep, sA + 4096 + t * 16);
    gl_lds16(Bb, sB + t * 16);
    gl_lds16(Bb + rowStep, sB + 4096 + t * 16);
    Ab += 64; Bb += 64;
    __syncthreads();

    bf16x8 af[4], bfr[4];
#pragma unroll
    for (int m = 0; m < 4; m++)
      af[m] = *(const bf16x8*)(sA + (wm * 64 + m * 16 + l15) * 64 + lg * 16);
#pragma unroll
    for (int n = 0; n < 4; n++)
      bfr[n] = *(const bf16x8*)(sB + (wn * 64 + n * 16 + l15) * 64 + lg * 16);
#pragma unroll
    for (int m = 0; m < 4; m++)
#pragma unroll
      for (int n = 0; n < 4; n++)
        acc[m][n] = __builtin_amdgcn_mfma_f32_16x16x32_bf16(af[m], bfr[n], acc[m][n], 0, 0, 0);
  }

#pragma unroll
  for (int m = 0; m < 4; m++) {
    int row = m0 + wm * 64 + m * 16 + 4 * lg;
#pragma unroll
    for (int n = 0; n < 4; n++) {
      int col = n0 + wn * 64 + n * 16 + l15;
#pragma unroll
      for (int i = 0; i < 4; i++)
        store_out(C + (size_t)(row + i) * N + col, acc[m][n][i]);
    }
  }
}

// ---------- flash attention (causal), swapped-QK^T layout ----------
// grid: (64 q-tiles, 16 heads), 256 threads = 4 waves, each wave 16 q rows.
// Q,K: [T, EMB] bf16 (head-sliced), Vt: [EMB, T] bf16. Output y: [T, EMB] bf16.
__global__ __launch_bounds__(256) void attn_kernel(const unsigned short* __restrict__ Q,
                                                   const unsigned short* __restrict__ Kp,
                                                   const unsigned short* __restrict__ Vt,
                                                   unsigned short* __restrict__ Y) {
  __shared__ char sK[16384];  // K tile [64 kv][128 hd] bf16, xor-swizzled
  __shared__ char sV[16384];  // Vt tile [128 hd][64 kv] bf16, xor-swizzled
  const int t = threadIdx.x, l = t & 63, w = t >> 6;
  const int lg = l >> 4, l15 = l & 15;
  const int h = blockIdx.y;
  const int q0 = (gridDim.x - 1 - blockIdx.x) * 64;  // heavy tiles dispatched first
  const int qrow = q0 + w * 16 + l15;                // this lane's q (S^T column)

  // Q fragments (B operand of S^T = K*Q): lane reads Q[qrow][kd*32 + 8*lg .. +7]
  bf16x8 qf[4];
#pragma unroll
  for (int kd = 0; kd < 4; kd++)
    qf[kd] = *(const bf16x8*)(Q + (size_t)qrow * EMB + h * HD + kd * 32 + lg * 8);

  f32x4 o[8] = {};
  float m_run = -1e30f, l_run = 0.0f;

  const int rK = t >> 4, cK = (t & 15) * 16;  // K staging: row within 16-row group, colbyte (256B rows)
  const int rV = t >> 3, cV = (t & 7) * 16;   // V staging: (128B rows)
  const char* Kb = (const char*)Kp;
  const char* Vb = (const char*)Vt;
  const float scale = 0.08838834764831845f;  // 1/sqrt(128)

  for (int kv0 = 0; kv0 <= q0; kv0 += 64) {
    __syncthreads();
#pragma unroll
    for (int c = 0; c < 4; c++) {
      int rowK = c * 16 + rK;
      gl_lds16(Kb + (size_t)(kv0 + rowK) * (EMB * 2) + h * (HD * 2) + (cK ^ ((rowK & 7) << 4)),
               sK + c * 4096 + t * 16);
      int rowV = c * 32 + rV;
      gl_lds16(Vb + (size_t)(h * HD + rowV) * (TSEQ * 2) + kv0 * 2 + (cV ^ ((rowV & 7) << 4)),
               sV + c * 4096 + t * 16);
    }
    __syncthreads();

    // S^T[kv, q] = K * Q^T : A = K frag (16kv x 32hd), B = Q frag
    f32x4 s[4] = {};
#pragma unroll
    for (int kvm = 0; kvm < 4; kvm++) {
      int rowT = kvm * 16 + l15;
#pragma unroll
      for (int kd = 0; kd < 4; kd++) {
        bf16x8 kf = *(const bf16x8*)(sK + rowT * 256 + ((kd * 64 + lg * 16) ^ ((rowT & 7) << 4)));
        s[kvm] = __builtin_amdgcn_mfma_f32_16x16x32_bf16(kf, qf[kd], s[kvm], 0, 0, 0);
      }
    }

    // scale + causal mask (only diagonal block)
    float bmax = -1e30f;
#pragma unroll
    for (int kvm = 0; kvm < 4; kvm++)
#pragma unroll
      for (int i = 0; i < 4; i++) {
        float x = s[kvm][i] * scale;
        if (kv0 == q0) {
          int kvg = kv0 + kvm * 16 + 4 * lg + i;
          if (kvg > qrow) x = -1e30f;
        }
        s[kvm][i] = x;
        bmax = fmaxf(bmax, x);
      }
    bmax = fmaxf(bmax, __shfl_xor(bmax, 16, 64));
    bmax = fmaxf(bmax, __shfl_xor(bmax, 32, 64));

    float m_new = fmaxf(m_run, bmax);
    float resc = __expf(m_run - m_new);
    float psum = 0.0f;
    unsigned int pb[4][2];
#pragma unroll
    for (int kvm = 0; kvm < 4; kvm++) {
      float p0 = __expf(s[kvm][0] - m_new);
      float p1 = __expf(s[kvm][1] - m_new);
      float p2 = __expf(s[kvm][2] - m_new);
      float p3 = __expf(s[kvm][3] - m_new);
      psum += (p0 + p1) + (p2 + p3);
      pb[kvm][0] = (unsigned)f2bf(p0) | ((unsigned)f2bf(p1) << 16);
      pb[kvm][1] = (unsigned)f2bf(p2) | ((unsigned)f2bf(p3) << 16);
    }
    psum += __shfl_xor(psum, 16, 64);
    psum += __shfl_xor(psum, 32, 64);
    l_run = l_run * resc + psum;
    m_run = m_new;
#pragma unroll
    for (int hdm = 0; hdm < 8; hdm++) {
      o[hdm][0] *= resc; o[hdm][1] *= resc; o[hdm][2] *= resc; o[hdm][3] *= resc;
    }

    // PV: O^T[hd,q] += V^T[hd,kv] * P^T[kv,q]; P^T B-frags gathered via shfl
    const int srcA = ((l & 16) << 1) + l15;  // group 2*(g&1)
    const int srcB = srcA + 16;
    const bool hi = (l & 32) != 0;           // dest groups 2,3 need frag 2c+1
#pragma unroll
    for (int c = 0; c < 2; c++) {
      unsigned int w0, w1, w2, w3;
      {
        unsigned int a0 = (unsigned)__shfl((int)pb[2 * c][0], srcA, 64);
        unsigned int a1 = (unsigned)__shfl((int)pb[2 * c][1], srcA, 64);
        unsigned int a2 = (unsigned)__shfl((int)pb[2 * c][0], srcB, 64);
        unsigned int a3 = (unsigned)__shfl((int)pb[2 * c][1], srcB, 64);
        unsigned int b0 = (unsigned)__shfl((int)pb[2 * c + 1][0], srcA, 64);
        unsigned int b1 = (unsigned)__shfl((int)pb[2 * c + 1][1], srcA, 64);
        unsigned int b2 = (unsigned)__shfl((int)pb[2 * c + 1][0], srcB, 64);
        unsigned int b3 = (unsigned)__shfl((int)pb[2 * c + 1][1], srcB, 64);
        w0 = hi ? b0 : a0; w1 = hi ? b1 : a1; w2 = hi ? b2 : a2; w3 = hi ? b3 : a3;
      }
      u32x4 pw; pw.x = w0; pw.y = w1; pw.z = w2; pw.w = w3;
      bf16x8 pfrag = __builtin_bit_cast(bf16x8, pw);
#pragma unroll
      for (int hdm = 0; hdm < 8; hdm++) {
        int rowV2 = hdm * 16 + l15;
        bf16x8 vf = *(const bf16x8*)(sV + rowV2 * 128 + ((c * 64 + lg * 16) ^ ((rowV2 & 7) << 4)));
        o[hdm] = __builtin_amdgcn_mfma_f32_16x16x32_bf16(vf, pfrag, o[hdm], 0, 0, 0);
      }
    }
  }

  float inv = 1.0f / l_run;
#pragma unroll
  for (int hdm = 0; hdm < 8; hdm++) {
    ushort4 st;
    st.x = f2bf(o[hdm][0] * inv);
    st.y = f2bf(o[hdm][1] * inv);
    st.z = f2bf(o[hdm][2] * inv);
    st.w = f2bf(o[hdm][3] * inv);
    *(ushort4*)(Y + (size_t)qrow * EMB + h * HD + hdm * 16 + 4 * lg) = st;
  }
}

// ---------- residual + LayerNorm (scale only) ----------
__global__ __launch_bounds__(256) void ln_kernel(const float* __restrict__ y2,
                                                 const float* __restrict__ qin,
                                                 const float* __restrict__ lnw,
                                                 float* __restrict__ out) {
  const int row = blockIdx.x, t = threadIdx.x;
  const float4* Y = (const float4*)(y2 + (size_t)row * EMB);
  const float4* Qv = (const float4*)(qin + (size_t)row * EMB);
  float4 a = Y[t], b = Qv[t];
  float4 x0, x1;
  x0.x = a.x + b.x; x0.y = a.y + b.y; x0.z = a.z + b.z; x0.w = a.w + b.w;
  a = Y[t + 256]; b = Qv[t + 256];
  x1.x = a.x + b.x; x1.y = a.y + b.y; x1.z = a.z + b.z; x1.w = a.w + b.w;
  float s = x0.x + x0.y + x0.z + x0.w + x1.x + x1.y + x1.z + x1.w;
  float s2 = x0.x * x0.x + x0.y * x0.y + x0.z * x0.z + x0.w * x0.w +
             x1.x * x1.x + x1.y * x1.y + x1.z * x1.z + x1.w * x1.w;
#pragma unroll
  for (int d = 1; d < 64; d <<= 1) {
    s += __shfl_xor(s, d, 64);
    s2 += __shfl_xor(s2, d, 64);
  }
  __shared__ float red[8];
  if ((t & 63) == 0) { red[(t >> 6) * 2] = s; red[(t >> 6) * 2 + 1] = s2; }
  __syncthreads();
  s = red[0] + red[2] + red[4] + red[6];
  s2 = red[1] + red[3] + red[5] + red[7];
  float mu = s * (1.0f / EMB);
  float var = s2 * (1.0f / EMB) - mu * mu;
  float r = rsqrtf(var + 1e-5f);
  float4 w0 = ((const float4*)lnw)[t], w1 = ((const float4*)lnw)[t + 256];
  float4 o0, o1;
  o0.x = (x0.x - mu) * r * w0.x; o0.y = (x0.y - mu) * r * w0.y;
  o0.z = (x0.z - mu) * r * w0.z; o0.w = (x0.w - mu) * r * w0.w;
  o1.x = (x1.x - mu) * r * w1.x; o1.y = (x1.y - mu) * r * w1.y;
  o1.z = (x1.z - mu) * r * w1.z; o1.w = (x1.w - mu) * r * w1.w;
  ((float4*)(out + (size_t)row * EMB))[t] = o0;
  ((float4*)(out + (size_t)row * EMB))[t + 256] = o1;
}

// ---------- launch ----------
extern "C" void kernel_launch(void* const* d_in, const int* in_sizes, int n_in,
                              void* d_out, int out_size, void* d_ws, size_t ws_size,
                              hipStream_t stream) {
  const float* q = (const float*)d_in[0];
  const float* k = (const float*)d_in[1];
  const float* v = (const float*)d_in[2];
  const float* Wq = (const float*)d_in[3];
  const float* Wk = (const float*)d_in[4];
  const float* Wv = (const float*)d_in[5];
  const float* Wo = (const float*)d_in[6];
  const float* lnw = (const float*)d_in[7];
  float* out = (float*)d_out;
  char* ws = (char*)d_ws;

  const size_t WB = (size_t)EMB * EMB * 2;       // 8 MB  (bf16 weight)
  const size_t XB = (size_t)TSEQ * EMB * 2;      // 16 MB (bf16 activation)
  unsigned short* Wq_b = (unsigned short*)(ws + 0 * WB);
  unsigned short* Wk_b = (unsigned short*)(ws + 1 * WB);
  unsigned short* Wv_b = (unsigned short*)(ws + 2 * WB);
  unsigned short* Wo_b = (unsigned short*)(ws + 3 * WB);
  unsigned short* qb   = (unsigned short*)(ws + 4 * WB);
  unsigned short* kb   = (unsigned short*)(ws + 4 * WB + XB);
  unsigned short* vb   = (unsigned short*)(ws + 4 * WB + 2 * XB);
  unsigned short* Qb   = (unsigned short*)(ws + 4 * WB + 3 * XB);
  unsigned short* Kb   = (unsigned short*)(ws + 4 * WB + 4 * XB);
  unsigned short* Vtb  = (unsigned short*)(ws + 4 * WB + 5 * XB);
  unsigned short* yb   = qb;                      // reuse (qb dead after Q proj)
  float* y2 = (float*)(ws + 4 * WB + XB);         // reuse kb+vb (dead after K/V proj)

  const int nW8 = EMB * EMB / 8, nX8 = TSEQ * EMB / 8;
  cvt_kernel<<<nW8 / 256, 256, 0, stream>>>(Wq, Wq_b, nW8);
  cvt_kernel<<<nW8 / 256, 256, 0, stream>>>(Wk, Wk_b, nW8);
  cvt_kernel<<<nW8 / 256, 256, 0, stream>>>(Wv, Wv_b, nW8);
  cvt_kernel<<<nW8 / 256, 256, 0, stream>>>(Wo, Wo_b, nW8);
  cvt_kernel<<<nX8 / 256, 256, 0, stream>>>(q, qb, nX8);
  cvt_kernel<<<nX8 / 256, 256, 0, stream>>>(k, kb, nX8);
  cvt_kernel<<<nX8 / 256, 256, 0, stream>>>(v, vb, nX8);

  gemm_nt<unsigned short><<<dim3(EMB / 128, TSEQ / 128), 256, 0, stream>>>(qb, Wq_b, Qb, TSEQ, EMB, EMB);
  gemm_nt<unsigned short><<<dim3(EMB / 128, TSEQ / 128), 256, 0, stream>>>(kb, Wk_b, Kb, TSEQ, EMB, EMB);
  gemm_nt<unsigned short><<<dim3(TSEQ / 128, EMB / 128), 256, 0, stream>>>(Wv_b, vb, Vtb, EMB, TSEQ, EMB);

  attn_kernel<<<dim3(TSEQ / 64, NH), 256, 0, stream>>>(Qb, Kb, Vtb, yb);

  gemm_nt<float><<<dim3(EMB / 128, TSEQ / 128), 256, 0, stream>>>(yb, Wo_b, y2, TSEQ, EMB, EMB);

  ln_kernel<<<TSEQ, 256, 0, stream>>>(y2, q, lnw, out);
}

// Round 2
// 446.598 us; speedup vs baseline: 1.2364x; 1.2364x over previous
//
#include <hip/hip_runtime.h>

typedef __bf16 bf16x8 __attribute__((ext_vector_type(8)));
typedef float f32x4 __attribute__((ext_vector_type(4)));
typedef unsigned int u32x4 __attribute__((ext_vector_type(4)));

#define EMB 2048
#define NH 16
#define HD 128
#define TSEQ 4096

// ---------- helpers ----------
__device__ __forceinline__ unsigned short f2bf(float x) {
  unsigned int u = __builtin_bit_cast(unsigned int, x);
  u += 0x7fffu + ((u >> 16) & 1u);   // RNE
  return (unsigned short)(u >> 16);
}

__device__ __forceinline__ void gl_lds16(const void* g, void* l) {
  __builtin_amdgcn_global_load_lds((__attribute__((address_space(1))) void*)(void*)g,
                                   (__attribute__((address_space(3))) void*)l, 16, 0, 0);
}

template <typename OutT>
__device__ __forceinline__ void store_out(OutT* p, float v) {
  if constexpr (sizeof(OutT) == 2) { *p = f2bf(v); } else { *p = v; }
}

// ---------- fp32 -> bf16 convert (vectorized 8/thread) ----------
__global__ __launch_bounds__(256) void cvt_kernel(const float* __restrict__ in,
                                                  unsigned short* __restrict__ outp, int n8) {
  int i = blockIdx.x * 256 + threadIdx.x;
  if (i >= n8) return;
  const float4* p = (const float4*)in + (size_t)i * 2;
  float4 a = p[0], b = p[1];
  u32x4 r;
  r.x = (unsigned)f2bf(a.x) | ((unsigned)f2bf(a.y) << 16);
  r.y = (unsigned)f2bf(a.z) | ((unsigned)f2bf(a.w) << 16);
  r.z = (unsigned)f2bf(b.x) | ((unsigned)f2bf(b.y) << 16);
  r.w = (unsigned)f2bf(b.z) | ((unsigned)f2bf(b.w) << 16);
  ((u32x4*)outp)[i] = r;
}

// ---------- NT GEMM: C[M,N] = A[M,K] * B[N,K]^T   (bf16 in, OutT out) ----------
template <typename OutT>
__global__ __launch_bounds__(256) void gemm_nt(const unsigned short* __restrict__ A,
                                               const unsigned short* __restrict__ B,
                                               OutT* __restrict__ C, int M, int N, int K) {
  __shared__ char smem[16384];
  char* sA = smem;
  char* sB = smem + 8192;
  const int t = threadIdx.x;
  const int m0 = blockIdx.y * 128, n0 = blockIdx.x * 128;
  const int l = t & 63, lg = l >> 4, l15 = l & 15;
  const int w = t >> 6, wm = w >> 1, wn = w & 1;

  f32x4 acc[4][4] = {};

  const int rowS = t >> 2;
  const int cbS = (t & 3) * 16;
  const char* Ab = (const char*)A + ((size_t)(m0 + rowS) * K) * 2 + cbS;
  const char* Bb = (const char*)B + ((size_t)(n0 + rowS) * K) * 2 + cbS;
  const size_t rowStep = (size_t)64 * K * 2;

  for (int kt = 0; kt < K; kt += 32) {
    __syncthreads();
    gl_lds16(Ab, sA + t * 16);
    gl_lds16(Ab + rowStep, sA + 4096 + t * 16);
    gl_lds16(Bb, sB + t * 16);
    gl_lds16(Bb + rowStep, sB + 4096 + t * 16);
    Ab += 64; Bb += 64;
    __syncthreads();

    bf16x8 af[4], bfr[4];
#pragma unroll
    for (int m = 0; m < 4; m++)
      af[m] = *(const bf16x8*)(sA + (wm * 64 + m * 16 + l15) * 64 + lg * 16);
#pragma unroll
    for (int n = 0; n < 4; n++)
      bfr[n] = *(const bf16x8*)(sB + (wn * 64 + n * 16 + l15) * 64 + lg * 16);
#pragma unroll
    for (int m = 0; m < 4; m++)
#pragma unroll
      for (int n = 0; n < 4; n++)
        acc[m][n] = __builtin_amdgcn_mfma_f32_16x16x32_bf16(af[m], bfr[n], acc[m][n], 0, 0, 0);
  }

#pragma unroll
  for (int m = 0; m < 4; m++) {
    int row = m0 + wm * 64 + m * 16 + 4 * lg;
#pragma unroll
    for (int n = 0; n < 4; n++) {
      int col = n0 + wn * 64 + n * 16 + l15;
#pragma unroll
      for (int i = 0; i < 4; i++)
        store_out(C + (size_t)(row + i) * N + col, acc[m][n][i]);
    }
  }
}

// ---------- flash attention (causal), swapped-QK^T, QBLK=32/wave, 2-phase pipeline ----------
// 512 blocks flat; head = b>>5, x = b&31, tile = (head<8)? x : 31-x  (complementary balance).
// Block covers 128 q rows (4 waves x 32). K,V double-buffered in LDS (64 KB).
__global__ __launch_bounds__(256, 2) void attn_kernel(const unsigned short* __restrict__ Q,
                                                      const unsigned short* __restrict__ Kp,
                                                      const unsigned short* __restrict__ Vt,
                                                      unsigned short* __restrict__ Y) {
  __shared__ char sK[2][16384];  // K tile [64 kv][128 hd] bf16, xor-swizzled
  __shared__ char sV[2][16384];  // Vt tile [128 hd][64 kv] bf16, xor-swizzled
  const int t = threadIdx.x, l = t & 63, w = t >> 6;
  const int lg = l >> 4, l15 = l & 15;
  const int b = blockIdx.x;
  const int h = b >> 5;
  const int x = b & 31;
  const int tile = (h < 8) ? x : 31 - x;
  const int q0 = tile * 128;
  const int nIter = 2 * tile + 2;          // kv blocks: 0 .. q0+64
  const int qrow0 = q0 + w * 32 + l15;     // g=0 row; g=1 row = +16

  bf16x8 qf[2][4];
#pragma unroll
  for (int g = 0; g < 2; g++)
#pragma unroll
    for (int kd = 0; kd < 4; kd++)
      qf[g][kd] = *(const bf16x8*)(Q + (size_t)(qrow0 + g * 16) * EMB + h * HD + kd * 32 + lg * 8);

  f32x4 o[2][8] = {};
  float m_run[2] = {-1e30f, -1e30f};
  float l_run[2] = {0.0f, 0.0f};

  const int rK = t >> 4, cK = (t & 15) * 16;  // K staging (256B rows)
  const int rV = t >> 3, cV = (t & 7) * 16;   // V staging (128B rows)
  const char* Kb = (const char*)Kp;
  const char* Vb = (const char*)Vt;
  const float scale = 0.08838834764831845f;   // 1/sqrt(128)

  auto stage = [&](int buf, int kv0) {
#pragma unroll
    for (int c = 0; c < 4; c++) {
      int rowK = c * 16 + rK;
      gl_lds16(Kb + (size_t)(kv0 + rowK) * (EMB * 2) + h * (HD * 2) + (cK ^ ((rowK & 7) << 4)),
               sK[buf] + c * 4096 + t * 16);
      int rowV = c * 32 + rV;
      gl_lds16(Vb + (size_t)(h * HD + rowV) * (TSEQ * 2) + kv0 * 2 + (cV ^ ((rowV & 7) << 4)),
               sV[buf] + c * 4096 + t * 16);
    }
  };

  stage(0, 0);
  int cur = 0;
  for (int it = 0; it < nIter; ++it) {
    const int kv0 = it * 64;
    if (it + 1 < nIter) {
      stage(cur ^ 1, kv0 + 64);                       // prefetch next tile
      asm volatile("s_waitcnt vmcnt(8)" ::: "memory");  // wait only for PREV stage
    } else {
      asm volatile("s_waitcnt vmcnt(0)" ::: "memory");
    }
    __builtin_amdgcn_s_barrier();

    const char* KB = sK[cur];
    const char* VB = sV[cur];

    // S^T[kv, q] = K * Q^T  (two q-groups share each K fragment)
    f32x4 s[2][4] = {};
#pragma unroll
    for (int kvm = 0; kvm < 4; kvm++) {
      const int rowT = kvm * 16 + l15;
      const int swz = (rowT & 7) << 4;
#pragma unroll
      for (int kd = 0; kd < 4; kd++) {
        bf16x8 kf = *(const bf16x8*)(KB + rowT * 256 + ((kd * 64 + lg * 16) ^ swz));
        s[0][kvm] = __builtin_amdgcn_mfma_f32_16x16x32_bf16(kf, qf[0][kd], s[0][kvm], 0, 0, 0);
        s[1][kvm] = __builtin_amdgcn_mfma_f32_16x16x32_bf16(kf, qf[1][kd], s[1][kvm], 0, 0, 0);
      }
    }

    const bool diag = (kv0 + 64 > q0);
    unsigned int pb[2][4][2];
#pragma unroll
    for (int g = 0; g < 2; g++) {
      const int qrow = qrow0 + g * 16;
      float bmax = -1e30f;
#pragma unroll
      for (int kvm = 0; kvm < 4; kvm++)
#pragma unroll
        for (int i = 0; i < 4; i++) {
          float xv = s[g][kvm][i] * scale;
          if (diag && (kv0 + kvm * 16 + 4 * lg + i > qrow)) xv = -1e30f;
          s[g][kvm][i] = xv;
          bmax = fmaxf(bmax, xv);
        }
      bmax = fmaxf(bmax, __shfl_xor(bmax, 16, 64));
      bmax = fmaxf(bmax, __shfl_xor(bmax, 32, 64));

      float m_new = fmaxf(m_run[g], bmax);
      float resc = __expf(m_run[g] - m_new);
      float psum = 0.0f;
#pragma unroll
      for (int kvm = 0; kvm < 4; kvm++) {
        float p0 = __expf(s[g][kvm][0] - m_new);
        float p1 = __expf(s[g][kvm][1] - m_new);
        float p2 = __expf(s[g][kvm][2] - m_new);
        float p3 = __expf(s[g][kvm][3] - m_new);
        psum += (p0 + p1) + (p2 + p3);
        pb[g][kvm][0] = (unsigned)f2bf(p0) | ((unsigned)f2bf(p1) << 16);
        pb[g][kvm][1] = (unsigned)f2bf(p2) | ((unsigned)f2bf(p3) << 16);
      }
      psum += __shfl_xor(psum, 16, 64);
      psum += __shfl_xor(psum, 32, 64);
      l_run[g] = l_run[g] * resc + psum;
      m_run[g] = m_new;
#pragma unroll
      for (int hdm = 0; hdm < 8; hdm++) o[g][hdm] *= resc;
    }

    // PV: O^T[hd,q] += V^T[hd,kv] * P^T[kv,q]; P^T B-frags gathered via shfl
    const int srcA = ((l & 16) << 1) + l15;
    const int srcB = srcA + 16;
    const bool hi = (l & 32) != 0;
#pragma unroll
    for (int c = 0; c < 2; c++) {
      bf16x8 pf[2];
#pragma unroll
      for (int g = 0; g < 2; g++) {
        unsigned int a0 = (unsigned)__shfl((int)pb[g][2 * c][0], srcA, 64);
        unsigned int a1 = (unsigned)__shfl((int)pb[g][2 * c][1], srcA, 64);
        unsigned int a2 = (unsigned)__shfl((int)pb[g][2 * c][0], srcB, 64);
        unsigned int a3 = (unsigned)__shfl((int)pb[g][2 * c][1], srcB, 64);
        unsigned int b0 = (unsigned)__shfl((int)pb[g][2 * c + 1][0], srcA, 64);
        unsigned int b1 = (unsigned)__shfl((int)pb[g][2 * c + 1][1], srcA, 64);
        unsigned int b2 = (unsigned)__shfl((int)pb[g][2 * c + 1][0], srcB, 64);
        unsigned int b3 = (unsigned)__shfl((int)pb[g][2 * c + 1][1], srcB, 64);
        u32x4 pw;
        pw.x = hi ? b0 : a0; pw.y = hi ? b1 : a1; pw.z = hi ? b2 : a2; pw.w = hi ? b3 : a3;
        pf[g] = __builtin_bit_cast(bf16x8, pw);
      }
#pragma unroll
      for (int hdm = 0; hdm < 8; hdm++) {
        const int rowV2 = hdm * 16 + l15;
        bf16x8 vf = *(const bf16x8*)(VB + rowV2 * 128 + ((c * 64 + lg * 16) ^ ((rowV2 & 7) << 4)));
        o[0][hdm] = __builtin_amdgcn_mfma_f32_16x16x32_bf16(vf, pf[0], o[0][hdm], 0, 0, 0);
        o[1][hdm] = __builtin_amdgcn_mfma_f32_16x16x32_bf16(vf, pf[1], o[1][hdm], 0, 0, 0);
      }
    }
    __builtin_amdgcn_s_barrier();   // all waves done reading buf[cur] before it is restaged
    cur ^= 1;
  }

#pragma unroll
  for (int g = 0; g < 2; g++) {
    float inv = 1.0f / l_run[g];
#pragma unroll
    for (int hdm = 0; hdm < 8; hdm++) {
      ushort4 st;
      st.x = f2bf(o[g][hdm][0] * inv);
      st.y = f2bf(o[g][hdm][1] * inv);
      st.z = f2bf(o[g][hdm][2] * inv);
      st.w = f2bf(o[g][hdm][3] * inv);
      *(ushort4*)(Y + (size_t)(qrow0 + g * 16) * EMB + h * HD + hdm * 16 + 4 * lg) = st;
    }
  }
}

// ---------- residual + LayerNorm (scale only) ----------
__global__ __launch_bounds__(256) void ln_kernel(const float* __restrict__ y2,
                                                 const float* __restrict__ qin,
                                                 const float* __restrict__ lnw,
                                                 float* __restrict__ out) {
  const int row = blockIdx.x, t = threadIdx.x;
  const float4* Y = (const float4*)(y2 + (size_t)row * EMB);
  const float4* Qv = (const float4*)(qin + (size_t)row * EMB);
  float4 a = Y[t], b = Qv[t];
  float4 x0, x1;
  x0.x = a.x + b.x; x0.y = a.y + b.y; x0.z = a.z + b.z; x0.w = a.w + b.w;
  a = Y[t + 256]; b = Qv[t + 256];
  x1.x = a.x + b.x; x1.y = a.y + b.y; x1.z = a.z + b.z; x1.w = a.w + b.w;
  float s = x0.x + x0.y + x0.z + x0.w + x1.x + x1.y + x1.z + x1.w;
  float s2 = x0.x * x0.x + x0.y * x0.y + x0.z * x0.z + x0.w * x0.w +
             x1.x * x1.x + x1.y * x1.y + x1.z * x1.z + x1.w * x1.w;
#pragma unroll
  for (int d = 1; d < 64; d <<= 1) {
    s += __shfl_xor(s, d, 64);
    s2 += __shfl_xor(s2, d, 64);
  }
  __shared__ float red[8];
  if ((t & 63) == 0) { red[(t >> 6) * 2] = s; red[(t >> 6) * 2 + 1] = s2; }
  __syncthreads();
  s = red[0] + red[2] + red[4] + red[6];
  s2 = red[1] + red[3] + red[5] + red[7];
  float mu = s * (1.0f / EMB);
  float var = s2 * (1.0f / EMB) - mu * mu;
  float r = rsqrtf(var + 1e-5f);
  float4 w0 = ((const float4*)lnw)[t], w1 = ((const float4*)lnw)[t + 256];
  float4 o0, o1;
  o0.x = (x0.x - mu) * r * w0.x; o0.y = (x0.y - mu) * r * w0.y;
  o0.z = (x0.z - mu) * r * w0.z; o0.w = (x0.w - mu) * r * w0.w;
  o1.x = (x1.x - mu) * r * w1.x; o1.y = (x1.y - mu) * r * w1.y;
  o1.z = (x1.z - mu) * r * w1.z; o1.w = (x1.w - mu) * r * w1.w;
  ((float4*)(out + (size_t)row * EMB))[t] = o0;
  ((float4*)(out + (size_t)row * EMB))[t + 256] = o1;
}

// ---------- launch ----------
extern "C" void kernel_launch(void* const* d_in, const int* in_sizes, int n_in,
                              void* d_out, int out_size, void* d_ws, size_t ws_size,
                              hipStream_t stream) {
  const float* q = (const float*)d_in[0];
  const float* k = (const float*)d_in[1];
  const float* v = (const float*)d_in[2];
  const float* Wq = (const float*)d_in[3];
  const float* Wk = (const float*)d_in[4];
  const float* Wv = (const float*)d_in[5];
  const float* Wo = (const float*)d_in[6];
  const float* lnw = (const float*)d_in[7];
  float* out = (float*)d_out;
  char* ws = (char*)d_ws;

  const size_t WB = (size_t)EMB * EMB * 2;       // 8 MB  (bf16 weight)
  const size_t XB = (size_t)TSEQ * EMB * 2;      // 16 MB (bf16 activation)
  unsigned short* Wq_b = (unsigned short*)(ws + 0 * WB);
  unsigned short* Wk_b = (unsigned short*)(ws + 1 * WB);
  unsigned short* Wv_b = (unsigned short*)(ws + 2 * WB);
  unsigned short* Wo_b = (unsigned short*)(ws + 3 * WB);
  unsigned short* qb   = (unsigned short*)(ws + 4 * WB);
  unsigned short* kb   = (unsigned short*)(ws + 4 * WB + XB);
  unsigned short* vb   = (unsigned short*)(ws + 4 * WB + 2 * XB);
  unsigned short* Qb   = (unsigned short*)(ws + 4 * WB + 3 * XB);
  unsigned short* Kb   = (unsigned short*)(ws + 4 * WB + 4 * XB);
  unsigned short* Vtb  = (unsigned short*)(ws + 4 * WB + 5 * XB);
  unsigned short* yb   = qb;                      // reuse (qb dead after Q proj)
  float* y2 = (float*)(ws + 4 * WB + XB);         // reuse kb+vb (dead after K/V proj)

  const int nW8 = EMB * EMB / 8, nX8 = TSEQ * EMB / 8;
  cvt_kernel<<<nW8 / 256, 256, 0, stream>>>(Wq, Wq_b, nW8);
  cvt_kernel<<<nW8 / 256, 256, 0, stream>>>(Wk, Wk_b, nW8);
  cvt_kernel<<<nW8 / 256, 256, 0, stream>>>(Wv, Wv_b, nW8);
  cvt_kernel<<<nW8 / 256, 256, 0, stream>>>(Wo, Wo_b, nW8);
  cvt_kernel<<<nX8 / 256, 256, 0, stream>>>(q, qb, nX8);
  cvt_kernel<<<nX8 / 256, 256, 0, stream>>>(k, kb, nX8);
  cvt_kernel<<<nX8 / 256, 256, 0, stream>>>(v, vb, nX8);

  gemm_nt<unsigned short><<<dim3(EMB / 128, TSEQ / 128), 256, 0, stream>>>(qb, Wq_b, Qb, TSEQ, EMB, EMB);
  gemm_nt<unsigned short><<<dim3(EMB / 128, TSEQ / 128), 256, 0, stream>>>(kb, Wk_b, Kb, TSEQ, EMB, EMB);
  gemm_nt<unsigned short><<<dim3(TSEQ / 128, EMB / 128), 256, 0, stream>>>(Wv_b, vb, Vtb, EMB, TSEQ, EMB);

  attn_kernel<<<dim3(512), 256, 0, stream>>>(Qb, Kb, Vtb, yb);

  gemm_nt<float><<<dim3(EMB / 128, TSEQ / 128), 256, 0, stream>>>(yb, Wo_b, y2, TSEQ, EMB, EMB);

  ln_kernel<<<TSEQ, 256, 0, stream>>>(y2, q, lnw, out);
}

// Round 3
// 377.999 us; speedup vs baseline: 1.4607x; 1.1815x over previous
//
#include <hip/hip_runtime.h>

typedef __bf16 bf16x8 __attribute__((ext_vector_type(8)));
typedef __bf16 bf16x2_t __attribute__((ext_vector_type(2)));
typedef float f32x4 __attribute__((ext_vector_type(4)));
typedef float f32x16 __attribute__((ext_vector_type(16)));
typedef unsigned int u32x4 __attribute__((ext_vector_type(4)));

#define EMB 2048
#define NH 16
#define HD 128
#define TSEQ 4096

// ---------- helpers ----------
__device__ __forceinline__ unsigned short f2bf(float x) {
  unsigned int u = __builtin_bit_cast(unsigned int, x);
  u += 0x7fffu + ((u >> 16) & 1u);   // RNE
  return (unsigned short)(u >> 16);
}

__device__ __forceinline__ void gl_lds16(const void* g, void* l) {
  __builtin_amdgcn_global_load_lds((__attribute__((address_space(1))) void*)(void*)g,
                                   (__attribute__((address_space(3))) void*)l, 16, 0, 0);
}

template <typename OutT>
__device__ __forceinline__ void store_out(OutT* p, float v) {
  if constexpr (sizeof(OutT) == 2) { *p = f2bf(v); } else { *p = v; }
}

// ---------- fused fp32 -> bf16 convert for all 7 tensors ----------
__global__ __launch_bounds__(256) void cvt_all(const float* __restrict__ q, const float* __restrict__ k,
                                               const float* __restrict__ v, const float* __restrict__ Wq,
                                               const float* __restrict__ Wk, const float* __restrict__ Wv,
                                               const float* __restrict__ Wo,
                                               unsigned short* qb, unsigned short* kb, unsigned short* vb,
                                               unsigned short* Wqb, unsigned short* Wkb, unsigned short* Wvb,
                                               unsigned short* Wob) {
  const int SX = TSEQ * EMB / 8;   // 2^20
  const int SW = EMB * EMB / 8;    // 2^19
  int i = blockIdx.x * 256 + threadIdx.x;
  const float* src; unsigned short* dst; int off;
  if (i < 3 * SX) {
    int seg = i >> 20; off = i & (SX - 1);
    src = (seg == 0) ? q : (seg == 1) ? k : v;
    dst = (seg == 0) ? qb : (seg == 1) ? kb : vb;
  } else {
    int j = i - 3 * SX;
    int seg = j >> 19; off = j & (SW - 1);
    src = (seg == 0) ? Wq : (seg == 1) ? Wk : (seg == 2) ? Wv : Wo;
    dst = (seg == 0) ? Wqb : (seg == 1) ? Wkb : (seg == 2) ? Wvb : Wob;
  }
  const float4* p = (const float4*)src + (size_t)off * 2;
  float4 a = p[0], b = p[1];
  u32x4 r;
  r.x = (unsigned)f2bf(a.x) | ((unsigned)f2bf(a.y) << 16);
  r.y = (unsigned)f2bf(a.z) | ((unsigned)f2bf(a.w) << 16);
  r.z = (unsigned)f2bf(b.x) | ((unsigned)f2bf(b.y) << 16);
  r.w = (unsigned)f2bf(b.z) | ((unsigned)f2bf(b.w) << 16);
  ((u32x4*)dst)[off] = r;
}

// ---------- NT GEMM body: C[M,N] = A[M,K] * B[N,K]^T  (128x128 tile, BK=32) ----------
template <typename OutT>
__device__ __forceinline__ void gemm_body(const unsigned short* __restrict__ A,
                                          const unsigned short* __restrict__ B,
                                          OutT* __restrict__ C,
                                          int m0, int n0, int N, int K, char* smem) {
  char* sA = smem;
  char* sB = smem + 8192;
  const int t = threadIdx.x;
  const int l = t & 63, lg = l >> 4, l15 = l & 15;
  const int w = t >> 6, wm = w >> 1, wn = w & 1;

  f32x4 acc[4][4] = {};

  const int rowS = t >> 2;
  const int cbS = (t & 3) * 16;
  const char* Ab = (const char*)A + ((size_t)(m0 + rowS) * K) * 2 + cbS;
  const char* Bb = (const char*)B + ((size_t)(n0 + rowS) * K) * 2 + cbS;
  const size_t rowStep = (size_t)64 * K * 2;

  for (int kt = 0; kt < K; kt += 32) {
    __syncthreads();
    gl_lds16(Ab, sA + t * 16);
    gl_lds16(Ab + rowStep, sA + 4096 + t * 16);
    gl_lds16(Bb, sB + t * 16);
    gl_lds16(Bb + rowStep, sB + 4096 + t * 16);
    Ab += 64; Bb += 64;
    __syncthreads();

    bf16x8 af[4], bfr[4];
#pragma unroll
    for (int m = 0; m < 4; m++)
      af[m] = *(const bf16x8*)(sA + (wm * 64 + m * 16 + l15) * 64 + lg * 16);
#pragma unroll
    for (int n = 0; n < 4; n++)
      bfr[n] = *(const bf16x8*)(sB + (wn * 64 + n * 16 + l15) * 64 + lg * 16);
#pragma unroll
    for (int m = 0; m < 4; m++)
#pragma unroll
      for (int n = 0; n < 4; n++)
        acc[m][n] = __builtin_amdgcn_mfma_f32_16x16x32_bf16(af[m], bfr[n], acc[m][n], 0, 0, 0);
  }

#pragma unroll
  for (int m = 0; m < 4; m++) {
    int row = m0 + wm * 64 + m * 16 + 4 * lg;
#pragma unroll
    for (int n = 0; n < 4; n++) {
      int col = n0 + wn * 64 + n * 16 + l15;
#pragma unroll
      for (int i = 0; i < 4; i++)
        store_out(C + (size_t)(row + i) * N + col, acc[m][n][i]);
    }
  }
}

// Fused Q/K/V projections: 1536 blocks; z = bx>>9 selects the GEMM.
__global__ __launch_bounds__(256) void gemm_qkv(const unsigned short* __restrict__ qb,
                                                const unsigned short* __restrict__ kb,
                                                const unsigned short* __restrict__ vb,
                                                const unsigned short* __restrict__ Wq,
                                                const unsigned short* __restrict__ Wk,
                                                const unsigned short* __restrict__ Wv,
                                                unsigned short* Qo, unsigned short* Ko, unsigned short* Vto) {
  __shared__ char smem[16384];
  const int bx = blockIdx.x;
  const int z = bx >> 9, r = bx & 511;
  const unsigned short* A; const unsigned short* B; unsigned short* C;
  int N, m0, n0;
  if (z == 0)      { A = qb; B = Wq; C = Qo;  N = EMB;  n0 = (r & 15) << 7; m0 = (r >> 4) << 7; }
  else if (z == 1) { A = kb; B = Wk; C = Ko;  N = EMB;  n0 = (r & 15) << 7; m0 = (r >> 4) << 7; }
  else             { A = Wv; B = vb; C = Vto; N = TSEQ; n0 = (r & 31) << 7; m0 = (r >> 5) << 7; }
  gemm_body<unsigned short>(A, B, C, m0, n0, N, EMB, smem);
}

__global__ __launch_bounds__(256) void gemm_o(const unsigned short* __restrict__ A,
                                              const unsigned short* __restrict__ B,
                                              float* __restrict__ C) {
  __shared__ char smem[16384];
  gemm_body<float>(A, B, C, blockIdx.y * 128, blockIdx.x * 128, EMB, EMB, smem);
}

// ---------- flash attention (causal), swapped-QK^T, 32x32x16 MFMA ----------
// 512 blocks; head = b>>5, x = b&31, tile = (head<8)? x : 31-x (complementary balance).
// Block = 128 q rows (4 waves x 32 q). K,V double-buffered in LDS (64 KB), xor-swizzled.
__global__ __launch_bounds__(256, 2) void attn_kernel(const unsigned short* __restrict__ Q,
                                                      const unsigned short* __restrict__ Kp,
                                                      const unsigned short* __restrict__ Vt,
                                                      unsigned short* __restrict__ Y) {
  __shared__ char sK[2][16384];  // [64 kv][128 hd] bf16, 256B rows
  __shared__ char sV[2][16384];  // [128 hd][64 kv] bf16, 128B rows
  const int t = threadIdx.x, l = t & 63, w = t >> 6;
  const int l31 = l & 31, hh = l >> 5;
  const int b = blockIdx.x;
  const int h = b >> 5;
  const int x = b & 31;
  const int tile = (h < 8) ? x : 31 - x;
  const int q0 = tile * 128;
  const int nIter = 2 * tile + 2;          // kv blocks 0 .. q0+64
  const int qrow = q0 + w * 32 + l31;      // this lane's q column

  // Q as B-operand frags: qf[kd] = Q[qrow][kd*16 + hh*8 .. +7]
  bf16x8 qf[8];
#pragma unroll
  for (int kd = 0; kd < 8; kd++)
    qf[kd] = *(const bf16x8*)(Q + (size_t)qrow * EMB + h * HD + kd * 16 + hh * 8);

  f32x16 o[4] = {};                        // O^T[hd= hdm*32 + creg][q]
  float m_run = -1e30f, l_run = 0.0f;

  const int rK = t >> 4, cK = (t & 15) * 16;
  const int rV = t >> 3, cV = (t & 7) * 16;
  const char* Kb = (const char*)Kp;
  const char* Vb = (const char*)Vt;
  const float SC = 0.08838834764831845f;   // 1/sqrt(128)

  auto stage = [&](int buf, int kv0) {
#pragma unroll
    for (int c = 0; c < 4; c++) {
      int rowK = c * 16 + rK;
      gl_lds16(Kb + (size_t)(kv0 + rowK) * (EMB * 2) + h * (HD * 2) + (cK ^ ((rowK & 7) << 4)),
               sK[buf] + c * 4096 + t * 16);
      int rowV = c * 32 + rV;
      gl_lds16(Vb + (size_t)(h * HD + rowV) * (TSEQ * 2) + kv0 * 2 + (cV ^ ((rowV & 7) << 4)),
               sV[buf] + c * 4096 + t * 16);
    }
  };

  stage(0, 0);
  int cur = 0;
  for (int it = 0; it < nIter; ++it) {
    const int kv0 = it * 64;
    if (it + 1 < nIter) {
      stage(cur ^ 1, kv0 + 64);
      asm volatile("s_waitcnt vmcnt(8)" ::: "memory");
    } else {
      asm volatile("s_waitcnt vmcnt(0)" ::: "memory");
    }
    __builtin_amdgcn_s_barrier();

    const char* KB = sK[cur];
    const char* VB = sV[cur];

    // S^T[kv,q]: A = K rows (32 kv), B = Q cols; 2 kvm x 8 kd MFMAs
    f32x16 s[2] = {};
    __builtin_amdgcn_s_setprio(1);
#pragma unroll
    for (int kvm = 0; kvm < 2; kvm++) {
      const int rowA = kvm * 32 + l31;
      const int swz = (rowA & 7) << 4;
#pragma unroll
      for (int kd = 0; kd < 8; kd++) {
        bf16x8 kf = *(const bf16x8*)(KB + rowA * 256 + ((kd * 32 + hh * 16) ^ swz));
        s[kvm] = __builtin_amdgcn_mfma_f32_32x32x16_bf16(kf, qf[kd], s[kvm], 0, 0, 0);
      }
    }
    __builtin_amdgcn_s_setprio(0);

    // scale + causal mask; lane owns one q column: kv(reg) = kvm*32 + (i&3)+8*(i>>2)+4*hh
    const bool diag = (kv0 + 64 > q0);
    float bmax = -1e30f;
#pragma unroll
    for (int kvm = 0; kvm < 2; kvm++)
#pragma unroll
      for (int i = 0; i < 16; i++) {
        float xv = s[kvm][i] * SC;
        if (diag && (kv0 + kvm * 32 + (i & 3) + 8 * (i >> 2) + 4 * hh > qrow)) xv = -1e30f;
        s[kvm][i] = xv;
        bmax = fmaxf(bmax, xv);
      }
    bmax = fmaxf(bmax, __shfl_xor(bmax, 32, 64));
    const float m_new = fmaxf(m_run, bmax);
    const float resc = __expf(m_run - m_new);
    float psum = 0.0f;
    unsigned int wb[16];   // bf16 pairs: word m of kvm covers kv = kvm*32 + 2*(m&1)+8*(m>>1)+4*hh
#pragma unroll
    for (int kvm = 0; kvm < 2; kvm++)
#pragma unroll
      for (int m = 0; m < 8; m++) {
        float p0 = __expf(s[kvm][2 * m + 0] - m_new);
        float p1 = __expf(s[kvm][2 * m + 1] - m_new);
        psum += p0 + p1;
        bf16x2_t pk; pk[0] = (__bf16)p0; pk[1] = (__bf16)p1;
        wb[kvm * 8 + m] = __builtin_bit_cast(unsigned int, pk);
      }
    psum += __shfl_xor(psum, 32, 64);
    l_run = l_run * resc + psum;
    m_run = m_new;
#pragma unroll
    for (int hdm = 0; hdm < 4; hdm++)
#pragma unroll
      for (int i = 0; i < 16; i++) o[hdm][i] *= resc;

    // PV: O^T += V^T * P^T; B-frag: k = 16*ks + 8*half + j, col = q
    __builtin_amdgcn_s_setprio(1);
#pragma unroll
    for (int kvm = 0; kvm < 2; kvm++)
#pragma unroll
      for (int sx = 0; sx < 2; sx++) {
        const int base = kvm * 8 + 4 * sx;
        const unsigned int a0 = wb[base + 0], a1 = wb[base + 1];
        const unsigned int b0 = wb[base + 2], b1 = wb[base + 3];
        const unsigned int snd0 = hh ? a0 : b0;     // what the partner half needs
        const unsigned int snd1 = hh ? a1 : b1;
        const unsigned int rcv0 = (unsigned int)__shfl_xor((int)snd0, 32, 64);
        const unsigned int rcv1 = (unsigned int)__shfl_xor((int)snd1, 32, 64);
        u32x4 pw;                                   // k-order: h'=0 pair, then h'=1 pair
        pw.x = hh ? rcv0 : a0;
        pw.y = hh ? rcv1 : a1;
        pw.z = hh ? b0 : rcv0;
        pw.w = hh ? b1 : rcv1;
        const bf16x8 pfrag = __builtin_bit_cast(bf16x8, pw);
        const int ks = kvm * 2 + sx;
#pragma unroll
        for (int hdm = 0; hdm < 4; hdm++) {
          const int rowA = hdm * 32 + l31;
          bf16x8 vf = *(const bf16x8*)(VB + rowA * 128 + ((ks * 32 + hh * 16) ^ ((rowA & 7) << 4)));
          o[hdm] = __builtin_amdgcn_mfma_f32_32x32x16_bf16(vf, pfrag, o[hdm], 0, 0, 0);
        }
      }
    __builtin_amdgcn_s_setprio(0);
    __builtin_amdgcn_s_barrier();
    cur ^= 1;
  }

  const float inv = 1.0f / l_run;
#pragma unroll
  for (int hdm = 0; hdm < 4; hdm++)
#pragma unroll
    for (int rq = 0; rq < 4; rq++) {
      ushort4 st;
      st.x = f2bf(o[hdm][4 * rq + 0] * inv);
      st.y = f2bf(o[hdm][4 * rq + 1] * inv);
      st.z = f2bf(o[hdm][4 * rq + 2] * inv);
      st.w = f2bf(o[hdm][4 * rq + 3] * inv);
      *(ushort4*)(Y + (size_t)qrow * EMB + h * HD + hdm * 32 + 8 * rq + 4 * hh) = st;
    }
}

// ---------- residual + LayerNorm (scale only) ----------
__global__ __launch_bounds__(256) void ln_kernel(const float* __restrict__ y2,
                                                 const float* __restrict__ qin,
                                                 const float* __restrict__ lnw,
                                                 float* __restrict__ out) {
  const int row = blockIdx.x, t = threadIdx.x;
  const float4* Y = (const float4*)(y2 + (size_t)row * EMB);
  const float4* Qv = (const float4*)(qin + (size_t)row * EMB);
  float4 a = Y[t], b = Qv[t];
  float4 x0, x1;
  x0.x = a.x + b.x; x0.y = a.y + b.y; x0.z = a.z + b.z; x0.w = a.w + b.w;
  a = Y[t + 256]; b = Qv[t + 256];
  x1.x = a.x + b.x; x1.y = a.y + b.y; x1.z = a.z + b.z; x1.w = a.w + b.w;
  float s = x0.x + x0.y + x0.z + x0.w + x1.x + x1.y + x1.z + x1.w;
  float s2 = x0.x * x0.x + x0.y * x0.y + x0.z * x0.z + x0.w * x0.w +
             x1.x * x1.x + x1.y * x1.y + x1.z * x1.z + x1.w * x1.w;
#pragma unroll
  for (int d = 1; d < 64; d <<= 1) {
    s += __shfl_xor(s, d, 64);
    s2 += __shfl_xor(s2, d, 64);
  }
  __shared__ float red[8];
  if ((t & 63) == 0) { red[(t >> 6) * 2] = s; red[(t >> 6) * 2 + 1] = s2; }
  __syncthreads();
  s = red[0] + red[2] + red[4] + red[6];
  s2 = red[1] + red[3] + red[5] + red[7];
  float mu = s * (1.0f / EMB);
  float var = s2 * (1.0f / EMB) - mu * mu;
  float r = rsqrtf(var + 1e-5f);
  float4 w0 = ((const float4*)lnw)[t], w1 = ((const float4*)lnw)[t + 256];
  float4 o0, o1;
  o0.x = (x0.x - mu) * r * w0.x; o0.y = (x0.y - mu) * r * w0.y;
  o0.z = (x0.z - mu) * r * w0.z; o0.w = (x0.w - mu) * r * w0.w;
  o1.x = (x1.x - mu) * r * w1.x; o1.y = (x1.y - mu) * r * w1.y;
  o1.z = (x1.z - mu) * r * w1.z; o1.w = (x1.w - mu) * r * w1.w;
  ((float4*)(out + (size_t)row * EMB))[t] = o0;
  ((float4*)(out + (size_t)row * EMB))[t + 256] = o1;
}

// ---------- launch ----------
extern "C" void kernel_launch(void* const* d_in, const int* in_sizes, int n_in,
                              void* d_out, int out_size, void* d_ws, size_t ws_size,
                              hipStream_t stream) {
  const float* q = (const float*)d_in[0];
  const float* k = (const float*)d_in[1];
  const float* v = (const float*)d_in[2];
  const float* Wq = (const float*)d_in[3];
  const float* Wk = (const float*)d_in[4];
  const float* Wv = (const float*)d_in[5];
  const float* Wo = (const float*)d_in[6];
  const float* lnw = (const float*)d_in[7];
  float* out = (float*)d_out;
  char* ws = (char*)d_ws;

  const size_t WB = (size_t)EMB * EMB * 2;       // 8 MB  (bf16 weight)
  const size_t XB = (size_t)TSEQ * EMB * 2;      // 16 MB (bf16 activation)
  unsigned short* Wq_b = (unsigned short*)(ws + 0 * WB);
  unsigned short* Wk_b = (unsigned short*)(ws + 1 * WB);
  unsigned short* Wv_b = (unsigned short*)(ws + 2 * WB);
  unsigned short* Wo_b = (unsigned short*)(ws + 3 * WB);
  unsigned short* qb   = (unsigned short*)(ws + 4 * WB);
  unsigned short* kb   = (unsigned short*)(ws + 4 * WB + XB);
  unsigned short* vb   = (unsigned short*)(ws + 4 * WB + 2 * XB);
  unsigned short* Qb   = (unsigned short*)(ws + 4 * WB + 3 * XB);
  unsigned short* Kb   = (unsigned short*)(ws + 4 * WB + 4 * XB);
  unsigned short* Vtb  = (unsigned short*)(ws + 4 * WB + 5 * XB);
  unsigned short* yb   = qb;                      // reuse (qb dead after QKV proj)
  float* y2 = (float*)(ws + 4 * WB + XB);         // reuse kb+vb (dead after QKV proj)

  cvt_all<<<20480, 256, 0, stream>>>(q, k, v, Wq, Wk, Wv, Wo,
                                     qb, kb, vb, Wq_b, Wk_b, Wv_b, Wo_b);

  gemm_qkv<<<1536, 256, 0, stream>>>(qb, kb, vb, Wq_b, Wk_b, Wv_b, Qb, Kb, Vtb);

  attn_kernel<<<512, 256, 0, stream>>>(Qb, Kb, Vtb, yb);

  gemm_o<<<dim3(16, 32), 256, 0, stream>>>(yb, Wo_b, y2);

  ln_kernel<<<TSEQ, 256, 0, stream>>>(y2, q, lnw, out);
}

// Round 4
// 352.595 us; speedup vs baseline: 1.5660x; 1.0720x over previous
//
#include <hip/hip_runtime.h>

typedef __bf16 bf16x8 __attribute__((ext_vector_type(8)));
typedef __bf16 bf16x2_t __attribute__((ext_vector_type(2)));
typedef float f32x4 __attribute__((ext_vector_type(4)));
typedef float f32x16 __attribute__((ext_vector_type(16)));
typedef unsigned int u32x4 __attribute__((ext_vector_type(4)));

#define EMB 2048
#define NH 16
#define HD 128
#define TSEQ 4096

// ---------- helpers ----------
__device__ __forceinline__ unsigned short f2bf(float x) {
  unsigned int u = __builtin_bit_cast(unsigned int, x);
  u += 0x7fffu + ((u >> 16) & 1u);   // RNE
  return (unsigned short)(u >> 16);
}

__device__ __forceinline__ float ex2(float x) { return __builtin_amdgcn_exp2f(x); }

__device__ __forceinline__ void gl_lds16(const void* g, void* l) {
  __builtin_amdgcn_global_load_lds((__attribute__((address_space(1))) void*)(void*)g,
                                   (__attribute__((address_space(3))) void*)l, 16, 0, 0);
}

template <typename OutT>
__device__ __forceinline__ void store_out(OutT* p, float v) {
  if constexpr (sizeof(OutT) == 2) { *p = f2bf(v); } else { *p = v; }
}

// ---------- fused fp32 -> bf16 convert for all 7 tensors ----------
__global__ __launch_bounds__(256) void cvt_all(const float* __restrict__ q, const float* __restrict__ k,
                                               const float* __restrict__ v, const float* __restrict__ Wq,
                                               const float* __restrict__ Wk, const float* __restrict__ Wv,
                                               const float* __restrict__ Wo,
                                               unsigned short* qb, unsigned short* kb, unsigned short* vb,
                                               unsigned short* Wqb, unsigned short* Wkb, unsigned short* Wvb,
                                               unsigned short* Wob) {
  const int SX = TSEQ * EMB / 8;   // 2^20
  const int SW = EMB * EMB / 8;    // 2^19
  int i = blockIdx.x * 256 + threadIdx.x;
  const float* src; unsigned short* dst; int off;
  if (i < 3 * SX) {
    int seg = i >> 20; off = i & (SX - 1);
    src = (seg == 0) ? q : (seg == 1) ? k : v;
    dst = (seg == 0) ? qb : (seg == 1) ? kb : vb;
  } else {
    int j = i - 3 * SX;
    int seg = j >> 19; off = j & (SW - 1);
    src = (seg == 0) ? Wq : (seg == 1) ? Wk : (seg == 2) ? Wv : Wo;
    dst = (seg == 0) ? Wqb : (seg == 1) ? Wkb : (seg == 2) ? Wvb : Wob;
  }
  const float4* p = (const float4*)src + (size_t)off * 2;
  float4 a = p[0], b = p[1];
  u32x4 r;
  r.x = (unsigned)f2bf(a.x) | ((unsigned)f2bf(a.y) << 16);
  r.y = (unsigned)f2bf(a.z) | ((unsigned)f2bf(a.w) << 16);
  r.z = (unsigned)f2bf(b.x) | ((unsigned)f2bf(b.y) << 16);
  r.w = (unsigned)f2bf(b.z) | ((unsigned)f2bf(b.w) << 16);
  ((u32x4*)dst)[off] = r;
}

// ---------- NT GEMM body: C[M,N] = A[M,K] * B[N,K]^T  (128x128 tile, BK=32) ----------
template <typename OutT>
__device__ __forceinline__ void gemm_body(const unsigned short* __restrict__ A,
                                          const unsigned short* __restrict__ B,
                                          OutT* __restrict__ C,
                                          int m0, int n0, int N, int K, char* smem, float oscale) {
  char* sA = smem;
  char* sB = smem + 8192;
  const int t = threadIdx.x;
  const int l = t & 63, lg = l >> 4, l15 = l & 15;
  const int w = t >> 6, wm = w >> 1, wn = w & 1;

  f32x4 acc[4][4] = {};

  const int rowS = t >> 2;
  const int cbS = (t & 3) * 16;
  const char* Ab = (const char*)A + ((size_t)(m0 + rowS) * K) * 2 + cbS;
  const char* Bb = (const char*)B + ((size_t)(n0 + rowS) * K) * 2 + cbS;
  const size_t rowStep = (size_t)64 * K * 2;

  for (int kt = 0; kt < K; kt += 32) {
    __syncthreads();
    gl_lds16(Ab, sA + t * 16);
    gl_lds16(Ab + rowStep, sA + 4096 + t * 16);
    gl_lds16(Bb, sB + t * 16);
    gl_lds16(Bb + rowStep, sB + 4096 + t * 16);
    Ab += 64; Bb += 64;
    __syncthreads();

    bf16x8 af[4], bfr[4];
#pragma unroll
    for (int m = 0; m < 4; m++)
      af[m] = *(const bf16x8*)(sA + (wm * 64 + m * 16 + l15) * 64 + lg * 16);
#pragma unroll
    for (int n = 0; n < 4; n++)
      bfr[n] = *(const bf16x8*)(sB + (wn * 64 + n * 16 + l15) * 64 + lg * 16);
#pragma unroll
    for (int m = 0; m < 4; m++)
#pragma unroll
      for (int n = 0; n < 4; n++)
        acc[m][n] = __builtin_amdgcn_mfma_f32_16x16x32_bf16(af[m], bfr[n], acc[m][n], 0, 0, 0);
  }

#pragma unroll
  for (int m = 0; m < 4; m++) {
    int row = m0 + wm * 64 + m * 16 + 4 * lg;
#pragma unroll
    for (int n = 0; n < 4; n++) {
      int col = n0 + wn * 64 + n * 16 + l15;
#pragma unroll
      for (int i = 0; i < 4; i++)
        store_out(C + (size_t)(row + i) * N + col, acc[m][n][i] * oscale);
    }
  }
}

// Fused Q/K/V projections: 1536 blocks; z = bx>>9 selects the GEMM.
// Q output is pre-scaled by 1/sqrt(HD) * log2(e) so attention softmax runs in exp2 domain.
__global__ __launch_bounds__(256) void gemm_qkv(const unsigned short* __restrict__ qb,
                                                const unsigned short* __restrict__ kb,
                                                const unsigned short* __restrict__ vb,
                                                const unsigned short* __restrict__ Wq,
                                                const unsigned short* __restrict__ Wk,
                                                const unsigned short* __restrict__ Wv,
                                                unsigned short* Qo, unsigned short* Ko, unsigned short* Vto) {
  __shared__ char smem[16384];
  const int bx = blockIdx.x;
  const int z = bx >> 9, r = bx & 511;
  const unsigned short* A; const unsigned short* B; unsigned short* C;
  int N, m0, n0; float sc;
  if (z == 0)      { A = qb; B = Wq; C = Qo;  N = EMB;  n0 = (r & 15) << 7; m0 = (r >> 4) << 7; sc = 0.12751743f; }
  else if (z == 1) { A = kb; B = Wk; C = Ko;  N = EMB;  n0 = (r & 15) << 7; m0 = (r >> 4) << 7; sc = 1.0f; }
  else             { A = Wv; B = vb; C = Vto; N = TSEQ; n0 = (r & 31) << 7; m0 = (r >> 5) << 7; sc = 1.0f; }
  gemm_body<unsigned short>(A, B, C, m0, n0, N, EMB, smem, sc);
}

__global__ __launch_bounds__(256) void gemm_o(const unsigned short* __restrict__ A,
                                              const unsigned short* __restrict__ B,
                                              float* __restrict__ C) {
  __shared__ char smem[16384];
  gemm_body<float>(A, B, C, blockIdx.y * 128, blockIdx.x * 128, EMB, EMB, smem, 1.0f);
}

// ---------- flash attention (causal), swapped-QK^T, 32x32x16 MFMA ----------
// 512 blocks; head = b>>5, x = b&31, tile = (head<8)? x : 31-x (complementary balance).
// Block = 128 q rows (4 waves x 32 q). K double-buffered, V triple-buffered in LDS (80 KB).
// Barriers live in the front half only; softmax+PV are barrier-free for cross-wave overlap.
__global__ __launch_bounds__(256, 2) void attn_kernel(const unsigned short* __restrict__ Q,
                                                      const unsigned short* __restrict__ Kp,
                                                      const unsigned short* __restrict__ Vt,
                                                      unsigned short* __restrict__ Y) {
  __shared__ char sK[2][16384];  // [64 kv][128 hd] bf16, 256B rows, xor-swz (&15)
  __shared__ char sV[3][16384];  // [128 hd][64 kv] bf16, 128B rows, xor-swz (&7)
  const int t = threadIdx.x, l = t & 63, w = t >> 6;
  const int l31 = l & 31, hh = l >> 5;
  const int b = blockIdx.x;
  const int h = b >> 5;
  const int x = b & 31;
  const int tile = (h < 8) ? x : 31 - x;
  const int q0 = tile * 128;
  const int nIter = 2 * tile + 2;          // kv blocks 0 .. q0+64
  const int qrow = q0 + w * 32 + l31;      // this lane's q column

  // Q as B-operand frags (already scaled by SC*log2e in projection epilogue)
  bf16x8 qf[8];
#pragma unroll
  for (int kd = 0; kd < 8; kd++)
    qf[kd] = *(const bf16x8*)(Q + (size_t)qrow * EMB + h * HD + kd * 16 + hh * 8);

  f32x16 o[4] = {};                        // O^T[hd = hdm*32 + creg][q]
  float m_run = -1e30f, l_run = 0.0f;

  const int rK = t >> 4, cK = (t & 15) * 16;
  const int rV = t >> 3, cV = (t & 7) * 16;
  const char* Kb = (const char*)Kp;
  const char* Vb = (const char*)Vt;

  auto stage = [&](int kbuf, int vbuf, int kv0) {
#pragma unroll
    for (int c = 0; c < 4; c++) {
      int rowK = c * 16 + rK;
      gl_lds16(Kb + (size_t)(kv0 + rowK) * (EMB * 2) + h * (HD * 2) + (cK ^ ((rowK & 15) << 4)),
               sK[kbuf] + c * 4096 + t * 16);
      int rowV = c * 32 + rV;
      gl_lds16(Vb + (size_t)(h * HD + rowV) * (TSEQ * 2) + kv0 * 2 + (cV ^ ((rowV & 7) << 4)),
               sV[vbuf] + c * 4096 + t * 16);
    }
  };

  stage(0, 0, 0);
  int kc = 0, vc = 0, vn = 1;
  for (int it = 0; it < nIter; ++it) {
    const int kv0 = it * 64;
    if (it + 1 < nIter) {
      stage(kc ^ 1, vn, kv0 + 64);
      asm volatile("s_waitcnt vmcnt(8)" ::: "memory");  // wait only for THIS tile's stage
    } else {
      asm volatile("s_waitcnt vmcnt(0)" ::: "memory");
    }
    __builtin_amdgcn_s_barrier();

    const char* KB = sK[kc];
    const char* VB = sV[vc];

    // S^T[kv,q]: A = K rows (32 kv), B = Q cols; 2 kvm x 8 kd MFMAs
    f32x16 s[2] = {};
    __builtin_amdgcn_s_setprio(1);
#pragma unroll
    for (int kvm = 0; kvm < 2; kvm++) {
      const int rowA = kvm * 32 + l31;
      const int swz = (rowA & 15) << 4;
#pragma unroll
      for (int kd = 0; kd < 8; kd++) {
        bf16x8 kf = *(const bf16x8*)(KB + rowA * 256 + ((kd * 32 + hh * 16) ^ swz));
        s[kvm] = __builtin_amdgcn_mfma_f32_32x32x16_bf16(kf, qf[kd], s[kvm], 0, 0, 0);
      }
    }
    __builtin_amdgcn_s_setprio(0);
    __builtin_amdgcn_s_barrier();   // K[kc] reads done -> next iter may restage it

    // ---- softmax (exp2 domain), barrier-free ----
    const bool diag = (kv0 + 64 > q0);
    if (diag) {
#pragma unroll
      for (int kvm = 0; kvm < 2; kvm++)
#pragma unroll
        for (int i = 0; i < 16; i++)
          if (kv0 + kvm * 32 + (i & 3) + 8 * (i >> 2) + 4 * hh > qrow) s[kvm][i] = -1e30f;
    }
    float bmax = -1e30f;
#pragma unroll
    for (int kvm = 0; kvm < 2; kvm++)
#pragma unroll
      for (int i = 0; i < 16; i++) bmax = fmaxf(bmax, s[kvm][i]);
    bmax = fmaxf(bmax, __shfl_xor(bmax, 32, 64));

    const bool skip = __all(bmax <= m_run + 8.0f);   // defer-rescale (T13)
    const float m_eff = skip ? m_run : fmaxf(m_run, bmax);

    float psum = 0.0f;
    unsigned int wb[16];   // bf16 pairs: word m of kvm covers kv = kvm*32 + 2*(m&1)+8*(m>>1)+4*hh
#pragma unroll
    for (int kvm = 0; kvm < 2; kvm++)
#pragma unroll
      for (int m = 0; m < 8; m++) {
        float p0 = ex2(s[kvm][2 * m + 0] - m_eff);
        float p1 = ex2(s[kvm][2 * m + 1] - m_eff);
        psum += p0 + p1;
        bf16x2_t pk; pk[0] = (__bf16)p0; pk[1] = (__bf16)p1;
        wb[kvm * 8 + m] = __builtin_bit_cast(unsigned int, pk);
      }
    psum += __shfl_xor(psum, 32, 64);
    if (!skip) {
      const float resc = ex2(m_run - m_eff);
#pragma unroll
      for (int hdm = 0; hdm < 4; hdm++)
#pragma unroll
        for (int i = 0; i < 16; i++) o[hdm][i] *= resc;
      l_run *= resc;
      m_run = m_eff;
    }
    l_run += psum;

    // ---- PV: O^T += V^T * P^T (barrier-free) ----
    __builtin_amdgcn_s_setprio(1);
#pragma unroll
    for (int kvm = 0; kvm < 2; kvm++)
#pragma unroll
      for (int sx = 0; sx < 2; sx++) {
        const int base = kvm * 8 + 4 * sx;
        const unsigned int a0 = wb[base + 0], a1 = wb[base + 1];
        const unsigned int b0 = wb[base + 2], b1 = wb[base + 3];
        const unsigned int snd0 = hh ? a0 : b0;
        const unsigned int snd1 = hh ? a1 : b1;
        const unsigned int rcv0 = (unsigned int)__shfl_xor((int)snd0, 32, 64);
        const unsigned int rcv1 = (unsigned int)__shfl_xor((int)snd1, 32, 64);
        u32x4 pw;
        pw.x = hh ? rcv0 : a0;
        pw.y = hh ? rcv1 : a1;
        pw.z = hh ? b0 : rcv0;
        pw.w = hh ? b1 : rcv1;
        const bf16x8 pfrag = __builtin_bit_cast(bf16x8, pw);
        const int ks = kvm * 2 + sx;
#pragma unroll
        for (int hdm = 0; hdm < 4; hdm++) {
          const int rowA = hdm * 32 + l31;
          bf16x8 vf = *(const bf16x8*)(VB + rowA * 128 + ((ks * 32 + hh * 16) ^ ((rowA & 7) << 4)));
          o[hdm] = __builtin_amdgcn_mfma_f32_32x32x16_bf16(vf, pfrag, o[hdm], 0, 0, 0);
        }
      }
    __builtin_amdgcn_s_setprio(0);

    kc ^= 1;
    vc = vn;
    vn = (vn == 2) ? 0 : vn + 1;
  }

  const float inv = 1.0f / l_run;
#pragma unroll
  for (int hdm = 0; hdm < 4; hdm++)
#pragma unroll
    for (int rq = 0; rq < 4; rq++) {
      ushort4 st;
      st.x = f2bf(o[hdm][4 * rq + 0] * inv);
      st.y = f2bf(o[hdm][4 * rq + 1] * inv);
      st.z = f2bf(o[hdm][4 * rq + 2] * inv);
      st.w = f2bf(o[hdm][4 * rq + 3] * inv);
      *(ushort4*)(Y + (size_t)qrow * EMB + h * HD + hdm * 32 + 8 * rq + 4 * hh) = st;
    }
}

// ---------- residual + LayerNorm (scale only) ----------
__global__ __launch_bounds__(256) void ln_kernel(const float* __restrict__ y2,
                                                 const float* __restrict__ qin,
                                                 const float* __restrict__ lnw,
                                                 float* __restrict__ out) {
  const int row = blockIdx.x, t = threadIdx.x;
  const float4* Y = (const float4*)(y2 + (size_t)row * EMB);
  const float4* Qv = (const float4*)(qin + (size_t)row * EMB);
  float4 a = Y[t], b = Qv[t];
  float4 x0, x1;
  x0.x = a.x + b.x; x0.y = a.y + b.y; x0.z = a.z + b.z; x0.w = a.w + b.w;
  a = Y[t + 256]; b = Qv[t + 256];
  x1.x = a.x + b.x; x1.y = a.y + b.y; x1.z = a.z + b.z; x1.w = a.w + b.w;
  float s = x0.x + x0.y + x0.z + x0.w + x1.x + x1.y + x1.z + x1.w;
  float s2 = x0.x * x0.x + x0.y * x0.y + x0.z * x0.z + x0.w * x0.w +
             x1.x * x1.x + x1.y * x1.y + x1.z * x1.z + x1.w * x1.w;
#pragma unroll
  for (int d = 1; d < 64; d <<= 1) {
    s += __shfl_xor(s, d, 64);
    s2 += __shfl_xor(s2, d, 64);
  }
  __shared__ float red[8];
  if ((t & 63) == 0) { red[(t >> 6) * 2] = s; red[(t >> 6) * 2 + 1] = s2; }
  __syncthreads();
  s = red[0] + red[2] + red[4] + red[6];
  s2 = red[1] + red[3] + red[5] + red[7];
  float mu = s * (1.0f / EMB);
  float var = s2 * (1.0f / EMB) - mu * mu;
  float r = rsqrtf(var + 1e-5f);
  float4 w0 = ((const float4*)lnw)[t], w1 = ((const float4*)lnw)[t + 256];
  float4 o0, o1;
  o0.x = (x0.x - mu) * r * w0.x; o0.y = (x0.y - mu) * r * w0.y;
  o0.z = (x0.z - mu) * r * w0.z; o0.w = (x0.w - mu) * r * w0.w;
  o1.x = (x1.x - mu) * r * w1.x; o1.y = (x1.y - mu) * r * w1.y;
  o1.z = (x1.z - mu) * r * w1.z; o1.w = (x1.w - mu) * r * w1.w;
  ((float4*)(out + (size_t)row * EMB))[t] = o0;
  ((float4*)(out + (size_t)row * EMB))[t + 256] = o1;
}

// ---------- launch ----------
extern "C" void kernel_launch(void* const* d_in, const int* in_sizes, int n_in,
                              void* d_out, int out_size, void* d_ws, size_t ws_size,
                              hipStream_t stream) {
  const float* q = (const float*)d_in[0];
  const float* k = (const float*)d_in[1];
  const float* v = (const float*)d_in[2];
  const float* Wq = (const float*)d_in[3];
  const float* Wk = (const float*)d_in[4];
  const float* Wv = (const float*)d_in[5];
  const float* Wo = (const float*)d_in[6];
  const float* lnw = (const float*)d_in[7];
  float* out = (float*)d_out;
  char* ws = (char*)d_ws;

  const size_t WB = (size_t)EMB * EMB * 2;       // 8 MB  (bf16 weight)
  const size_t XB = (size_t)TSEQ * EMB * 2;      // 16 MB (bf16 activation)
  unsigned short* Wq_b = (unsigned short*)(ws + 0 * WB);
  unsigned short* Wk_b = (unsigned short*)(ws + 1 * WB);
  unsigned short* Wv_b = (unsigned short*)(ws + 2 * WB);
  unsigned short* Wo_b = (unsigned short*)(ws + 3 * WB);
  unsigned short* qb   = (unsigned short*)(ws + 4 * WB);
  unsigned short* kb   = (unsigned short*)(ws + 4 * WB + XB);
  unsigned short* vb   = (unsigned short*)(ws + 4 * WB + 2 * XB);
  unsigned short* Qb   = (unsigned short*)(ws + 4 * WB + 3 * XB);
  unsigned short* Kb   = (unsigned short*)(ws + 4 * WB + 4 * XB);
  unsigned short* Vtb  = (unsigned short*)(ws + 4 * WB + 5 * XB);
  unsigned short* yb   = qb;                      // reuse (qb dead after QKV proj)
  float* y2 = (float*)(ws + 4 * WB + XB);         // reuse kb+vb (dead after QKV proj)

  cvt_all<<<20480, 256, 0, stream>>>(q, k, v, Wq, Wk, Wv, Wo,
                                     qb, kb, vb, Wq_b, Wk_b, Wv_b, Wo_b);

  gemm_qkv<<<1536, 256, 0, stream>>>(qb, kb, vb, Wq_b, Wk_b, Wv_b, Qb, Kb, Vtb);

  attn_kernel<<<512, 256, 0, stream>>>(Qb, Kb, Vtb, yb);

  gemm_o<<<dim3(16, 32), 256, 0, stream>>>(yb, Wo_b, y2);

  ln_kernel<<<TSEQ, 256, 0, stream>>>(y2, q, lnw, out);
}

// Round 5
// 330.888 us; speedup vs baseline: 1.6687x; 1.0656x over previous
//
#include <hip/hip_runtime.h>

typedef __bf16 bf16x8 __attribute__((ext_vector_type(8)));
typedef __bf16 bf16x2_t __attribute__((ext_vector_type(2)));
typedef float f32x4 __attribute__((ext_vector_type(4)));
typedef float f32x16 __attribute__((ext_vector_type(16)));
typedef unsigned int u32x4 __attribute__((ext_vector_type(4)));
typedef unsigned short u16x8 __attribute__((ext_vector_type(8)));

#define EMB 2048
#define NH 16
#define HD 128
#define TSEQ 4096

// ---------- helpers ----------
__device__ __forceinline__ unsigned short f2bf(float x) {
  unsigned int u = __builtin_bit_cast(unsigned int, x);
  u += 0x7fffu + ((u >> 16) & 1u);   // RNE
  return (unsigned short)(u >> 16);
}

__device__ __forceinline__ float bf2f(unsigned short u) {
  unsigned int x = ((unsigned int)u) << 16;
  return __builtin_bit_cast(float, x);
}

__device__ __forceinline__ float ex2(float x) { return __builtin_amdgcn_exp2f(x); }

__device__ __forceinline__ void gl_lds16(const void* g, void* l) {
  __builtin_amdgcn_global_load_lds((__attribute__((address_space(1))) void*)(void*)g,
                                   (__attribute__((address_space(3))) void*)l, 16, 0, 0);
}

template <typename OutT>
__device__ __forceinline__ void store_out(OutT* p, float v) {
  if constexpr (sizeof(OutT) == 2) { *p = f2bf(v); } else { *p = v; }
}

// ---------- fused fp32 -> bf16 convert for all 7 tensors ----------
__global__ __launch_bounds__(256) void cvt_all(const float* __restrict__ q, const float* __restrict__ k,
                                               const float* __restrict__ v, const float* __restrict__ Wq,
                                               const float* __restrict__ Wk, const float* __restrict__ Wv,
                                               const float* __restrict__ Wo,
                                               unsigned short* qb, unsigned short* kb, unsigned short* vb,
                                               unsigned short* Wqb, unsigned short* Wkb, unsigned short* Wvb,
                                               unsigned short* Wob) {
  const int SX = TSEQ * EMB / 8;   // 2^20
  const int SW = EMB * EMB / 8;    // 2^19
  int i = blockIdx.x * 256 + threadIdx.x;
  const float* src; unsigned short* dst; int off;
  if (i < 3 * SX) {
    int seg = i >> 20; off = i & (SX - 1);
    src = (seg == 0) ? q : (seg == 1) ? k : v;
    dst = (seg == 0) ? qb : (seg == 1) ? kb : vb;
  } else {
    int j = i - 3 * SX;
    int seg = j >> 19; off = j & (SW - 1);
    src = (seg == 0) ? Wq : (seg == 1) ? Wk : (seg == 2) ? Wv : Wo;
    dst = (seg == 0) ? Wqb : (seg == 1) ? Wkb : (seg == 2) ? Wvb : Wob;
  }
  const float4* p = (const float4*)src + (size_t)off * 2;
  float4 a = p[0], b = p[1];
  u32x4 r;
  r.x = (unsigned)f2bf(a.x) | ((unsigned)f2bf(a.y) << 16);
  r.y = (unsigned)f2bf(a.z) | ((unsigned)f2bf(a.w) << 16);
  r.z = (unsigned)f2bf(b.x) | ((unsigned)f2bf(b.y) << 16);
  r.w = (unsigned)f2bf(b.z) | ((unsigned)f2bf(b.w) << 16);
  ((u32x4*)dst)[off] = r;
}

// ---------- NT GEMM body: C[M,N] = A[M,K] * B[N,K]^T  (128x128 tile, BK=32) ----------
template <typename OutT>
__device__ __forceinline__ void gemm_body(const unsigned short* __restrict__ A,
                                          const unsigned short* __restrict__ B,
                                          OutT* __restrict__ C,
                                          int m0, int n0, int N, int K, char* smem, float oscale) {
  char* sA = smem;
  char* sB = smem + 8192;
  const int t = threadIdx.x;
  const int l = t & 63, lg = l >> 4, l15 = l & 15;
  const int w = t >> 6, wm = w >> 1, wn = w & 1;

  f32x4 acc[4][4] = {};

  const int rowS = t >> 2;
  const int cbS = (t & 3) * 16;
  const char* Ab = (const char*)A + ((size_t)(m0 + rowS) * K) * 2 + cbS;
  const char* Bb = (const char*)B + ((size_t)(n0 + rowS) * K) * 2 + cbS;
  const size_t rowStep = (size_t)64 * K * 2;

  for (int kt = 0; kt < K; kt += 32) {
    __syncthreads();
    gl_lds16(Ab, sA + t * 16);
    gl_lds16(Ab + rowStep, sA + 4096 + t * 16);
    gl_lds16(Bb, sB + t * 16);
    gl_lds16(Bb + rowStep, sB + 4096 + t * 16);
    Ab += 64; Bb += 64;
    __syncthreads();

    bf16x8 af[4], bfr[4];
#pragma unroll
    for (int m = 0; m < 4; m++)
      af[m] = *(const bf16x8*)(sA + (wm * 64 + m * 16 + l15) * 64 + lg * 16);
#pragma unroll
    for (int n = 0; n < 4; n++)
      bfr[n] = *(const bf16x8*)(sB + (wn * 64 + n * 16 + l15) * 64 + lg * 16);
#pragma unroll
    for (int m = 0; m < 4; m++)
#pragma unroll
      for (int n = 0; n < 4; n++)
        acc[m][n] = __builtin_amdgcn_mfma_f32_16x16x32_bf16(af[m], bfr[n], acc[m][n], 0, 0, 0);
  }

#pragma unroll
  for (int m = 0; m < 4; m++) {
    int row = m0 + wm * 64 + m * 16 + 4 * lg;
#pragma unroll
    for (int n = 0; n < 4; n++) {
      int col = n0 + wn * 64 + n * 16 + l15;
#pragma unroll
      for (int i = 0; i < 4; i++)
        store_out(C + (size_t)(row + i) * N + col, acc[m][n][i] * oscale);
    }
  }
}

// Fused Q/K/V projections: 1536 blocks; z = bx>>9 selects the GEMM.
// Q output pre-scaled by 1/sqrt(HD)*log2(e) so attention softmax runs in exp2 domain.
__global__ __launch_bounds__(256) void gemm_qkv(const unsigned short* __restrict__ qb,
                                                const unsigned short* __restrict__ kb,
                                                const unsigned short* __restrict__ vb,
                                                const unsigned short* __restrict__ Wq,
                                                const unsigned short* __restrict__ Wk,
                                                const unsigned short* __restrict__ Wv,
                                                unsigned short* Qo, unsigned short* Ko, unsigned short* Vto) {
  __shared__ char smem[16384];
  const int bx = blockIdx.x;
  const int z = bx >> 9, r = bx & 511;
  const unsigned short* A; const unsigned short* B; unsigned short* C;
  int N, m0, n0; float sc;
  if (z == 0)      { A = qb; B = Wq; C = Qo;  N = EMB;  n0 = (r & 15) << 7; m0 = (r >> 4) << 7; sc = 0.12751743f; }
  else if (z == 1) { A = kb; B = Wk; C = Ko;  N = EMB;  n0 = (r & 15) << 7; m0 = (r >> 4) << 7; sc = 1.0f; }
  else             { A = Wv; B = vb; C = Vto; N = TSEQ; n0 = (r & 31) << 7; m0 = (r >> 5) << 7; sc = 1.0f; }
  gemm_body<unsigned short>(A, B, C, m0, n0, N, EMB, smem, sc);
}

__global__ __launch_bounds__(256) void gemm_o(const unsigned short* __restrict__ A,
                                              const unsigned short* __restrict__ B,
                                              float* __restrict__ C) {
  __shared__ char smem[16384];
  gemm_body<float>(A, B, C, blockIdx.y * 128, blockIdx.x * 128, EMB, EMB, smem, 1.0f);
}

// ---------- flash attention (causal), swapped-QK^T, 32x32x16 MFMA, static-max softmax ----------
// 512 UNIFORM blocks of exactly 33 kv-iterations each.
// Pair (p, 31-p) per head: block(h,p,0) = tile p complete (2p+2 iters) + tile 31-p kv-blocks
// [0, 31-2p); block(h,p,1) = tile 31-p kv-blocks [31-2p, 63-2p]. Static max M=8 makes
// partials sum-mergeable (no max bookkeeping). Partial O (bf16) + l (f32) go to slots.
__global__ __launch_bounds__(256, 2) void attn_kernel(const unsigned short* __restrict__ Q,
                                                      const unsigned short* __restrict__ Kp,
                                                      const unsigned short* __restrict__ Vt,
                                                      unsigned short* __restrict__ slots,
                                                      float* __restrict__ lbuf) {
  __shared__ char sK[2][16384];  // [64 kv][128 hd] bf16, 256B rows, xor-swz (&15)
  __shared__ char sV[3][16384];  // [128 hd][64 kv] bf16, 128B rows, xor-swz (&7)
  const int t = threadIdx.x, l = t & 63, w = t >> 6;
  const int l31 = l & 31, hh = l >> 5;
  const int b = blockIdx.x;
  const int h = b >> 5;
  const int p = (b >> 1) & 15;
  const int half = b & 1;
  const int slotBase = (h * 16 + p) * 3;

  const int q0A = 128 * p, q0B = 128 * (31 - p);
  const int swi = (half == 0) ? (2 * p + 2) : 64;   // gi at which tile B starts (64 = never)
  const int kvOff = 31 - 2 * p;                     // half-1 kv-block offset

  int q0 = (half == 0) ? q0A : q0B;
  int qrow = q0 + w * 32 + l31;

  auto kvof = [&](int gi) -> int {
    if (half == 0) return (gi < swi) ? gi * 64 : (gi - swi) * 64;
    return (kvOff + gi) * 64;
  };

  // Q as B-operand frags (already scaled by SC*log2e in projection epilogue)
  bf16x8 qf[8];
#pragma unroll
  for (int kd = 0; kd < 8; kd++)
    qf[kd] = *(const bf16x8*)(Q + (size_t)qrow * EMB + h * HD + kd * 16 + hh * 8);

  f32x16 o[4] = {};                        // O^T[hd = hdm*32 + creg][q], unnormalized
  float l_run = 0.0f;                      // per half-wave; combined at writeout

  const int rK = t >> 4, cK = (t & 15) * 16;
  const int rV = t >> 3, cV = (t & 7) * 16;
  const char* Kb = (const char*)Kp;
  const char* Vb = (const char*)Vt;

  auto stage = [&](int kbuf, int vbuf, int kv0) {
#pragma unroll
    for (int c = 0; c < 4; c++) {
      int rowK = c * 16 + rK;
      gl_lds16(Kb + (size_t)(kv0 + rowK) * (EMB * 2) + h * (HD * 2) + (cK ^ ((rowK & 15) << 4)),
               sK[kbuf] + c * 4096 + t * 16);
      int rowV = c * 32 + rV;
      gl_lds16(Vb + (size_t)(h * HD + rowV) * (TSEQ * 2) + kv0 * 2 + (cV ^ ((rowV & 7) << 4)),
               sV[vbuf] + c * 4096 + t * 16);
    }
  };

  auto writeout = [&](int slotId) {
    unsigned short* S = slots + (size_t)slotId * (128 * 128);
    const int r = w * 32 + l31;
    float lt = l_run + __shfl_xor(l_run, 32, 64);
    if (hh == 0) lbuf[slotId * 128 + r] = lt;
#pragma unroll
    for (int hdm = 0; hdm < 4; hdm++)
#pragma unroll
      for (int rq = 0; rq < 4; rq++) {
        ushort4 st;
        st.x = f2bf(o[hdm][4 * rq + 0]);
        st.y = f2bf(o[hdm][4 * rq + 1]);
        st.z = f2bf(o[hdm][4 * rq + 2]);
        st.w = f2bf(o[hdm][4 * rq + 3]);
        *(ushort4*)(S + r * 128 + hdm * 32 + 8 * rq + 4 * hh) = st;
      }
  };

  stage(0, 0, kvof(0));
  int kc = 0, vc = 0, vn = 1;
  for (int gi = 0; gi < 33; ++gi) {
    if (half == 0 && gi == swi) {
      // tile A complete: flush, reset, switch to tile B
      writeout(slotBase + 0);
#pragma unroll
      for (int hdm = 0; hdm < 4; hdm++)
#pragma unroll
        for (int i = 0; i < 16; i++) o[hdm][i] = 0.0f;
      l_run = 0.0f;
      q0 = q0B;
      qrow = q0 + w * 32 + l31;
#pragma unroll
      for (int kd = 0; kd < 8; kd++)
        qf[kd] = *(const bf16x8*)(Q + (size_t)qrow * EMB + h * HD + kd * 16 + hh * 8);
    }
    const int kv0 = kvof(gi);
    if (gi + 1 < 33) {
      stage(kc ^ 1, vn, kvof(gi + 1));
      asm volatile("s_waitcnt vmcnt(8)" ::: "memory");  // wait only for THIS tile's stage
    } else {
      asm volatile("s_waitcnt vmcnt(0)" ::: "memory");
    }
    __builtin_amdgcn_s_barrier();

    const char* KB = sK[kc];
    const char* VB = sV[vc];

    // S^T[kv,q]: A = K rows (32 kv), B = Q cols; acc init -8 = static-max shift
    f32x16 s[2];
#pragma unroll
    for (int i = 0; i < 16; i++) { s[0][i] = -8.0f; s[1][i] = -8.0f; }
    __builtin_amdgcn_s_setprio(1);
#pragma unroll
    for (int kvm = 0; kvm < 2; kvm++) {
      const int rowA = kvm * 32 + l31;
      const int swz = (rowA & 15) << 4;
#pragma unroll
      for (int kd = 0; kd < 8; kd++) {
        bf16x8 kf = *(const bf16x8*)(KB + rowA * 256 + ((kd * 32 + hh * 16) ^ swz));
        s[kvm] = __builtin_amdgcn_mfma_f32_32x32x16_bf16(kf, qf[kd], s[kvm], 0, 0, 0);
      }
    }
    __builtin_amdgcn_s_setprio(0);
    __builtin_amdgcn_s_barrier();   // K[kc] reads done -> next iter may restage it

    // ---- static-max softmax (exp2 domain): p = exp2(s - 8), no max/rescale/shfl ----
    const bool diag = (kv0 + 64 > q0);
    if (diag) {
#pragma unroll
      for (int kvm = 0; kvm < 2; kvm++)
#pragma unroll
        for (int i = 0; i < 16; i++)
          if (kv0 + kvm * 32 + (i & 3) + 8 * (i >> 2) + 4 * hh > qrow) s[kvm][i] = -1e30f;
    }
    float psum = 0.0f;
    unsigned int wb[16];   // bf16 pairs: word m of kvm covers kv = kvm*32 + 2*(m&1)+8*(m>>1)+4*hh
#pragma unroll
    for (int kvm = 0; kvm < 2; kvm++)
#pragma unroll
      for (int m = 0; m < 8; m++) {
        float p0 = ex2(s[kvm][2 * m + 0]);
        float p1 = ex2(s[kvm][2 * m + 1]);
        psum += p0 + p1;
        bf16x2_t pk; pk[0] = (__bf16)p0; pk[1] = (__bf16)p1;
        wb[kvm * 8 + m] = __builtin_bit_cast(unsigned int, pk);
      }
    l_run += psum;

    // ---- PV: O^T += V^T * P^T (barrier-free) ----
    __builtin_amdgcn_s_setprio(1);
#pragma unroll
    for (int kvm = 0; kvm < 2; kvm++)
#pragma unroll
      for (int sx = 0; sx < 2; sx++) {
        const int base = kvm * 8 + 4 * sx;
        const unsigned int a0 = wb[base + 0], a1 = wb[base + 1];
        const unsigned int b0 = wb[base + 2], b1 = wb[base + 3];
        const unsigned int snd0 = hh ? a0 : b0;
        const unsigned int snd1 = hh ? a1 : b1;
        const unsigned int rcv0 = (unsigned int)__shfl_xor((int)snd0, 32, 64);
        const unsigned int rcv1 = (unsigned int)__shfl_xor((int)snd1, 32, 64);
        u32x4 pw;
        pw.x = hh ? rcv0 : a0;
        pw.y = hh ? rcv1 : a1;
        pw.z = hh ? b0 : rcv0;
        pw.w = hh ? b1 : rcv1;
        const bf16x8 pfrag = __builtin_bit_cast(bf16x8, pw);
        const int ks = kvm * 2 + sx;
#pragma unroll
        for (int hdm = 0; hdm < 4; hdm++) {
          const int rowA = hdm * 32 + l31;
          bf16x8 vf = *(const bf16x8*)(VB + rowA * 128 + ((ks * 32 + hh * 16) ^ ((rowA & 7) << 4)));
          o[hdm] = __builtin_amdgcn_mfma_f32_32x32x16_bf16(vf, pfrag, o[hdm], 0, 0, 0);
        }
      }
    __builtin_amdgcn_s_setprio(0);

    kc ^= 1;
    vc = vn;
    vn = (vn == 2) ? 0 : vn + 1;
  }

  writeout(slotBase + ((half == 0) ? 1 : 2));
}

// ---------- merge partials -> normalized bf16 y ----------
// 512 blocks = (head, tile). tile<=15: slot A only; else B0+B1.
__global__ __launch_bounds__(256) void merge_kernel(const unsigned short* __restrict__ slots,
                                                    const float* __restrict__ lbuf,
                                                    unsigned short* __restrict__ Y) {
  const int tile = blockIdx.x;
  const int h = tile >> 5, tt = tile & 31;
  const int p = (tt <= 15) ? tt : 31 - tt;
  const int base = (h * 16 + p) * 3;
  const int t = threadIdx.x;
  const int r = t >> 1;
  const int c0 = (t & 1) * 64;
  unsigned short* yp = Y + (size_t)(128 * tt + r) * EMB + h * HD + c0;
  if (tt <= 15) {
    const unsigned short* S = slots + (size_t)(base + 0) * (128 * 128) + r * 128 + c0;
    const float inv = 1.0f / lbuf[(base + 0) * 128 + r];
#pragma unroll
    for (int j = 0; j < 8; j++) {
      u16x8 a = ((const u16x8*)S)[j];
      u16x8 ov;
#pragma unroll
      for (int e = 0; e < 8; e++) ov[e] = f2bf(bf2f(a[e]) * inv);
      ((u16x8*)yp)[j] = ov;
    }
  } else {
    const unsigned short* S0 = slots + (size_t)(base + 1) * (128 * 128) + r * 128 + c0;
    const unsigned short* S1 = slots + (size_t)(base + 2) * (128 * 128) + r * 128 + c0;
    const float inv = 1.0f / (lbuf[(base + 1) * 128 + r] + lbuf[(base + 2) * 128 + r]);
#pragma unroll
    for (int j = 0; j < 8; j++) {
      u16x8 a = ((const u16x8*)S0)[j];
      u16x8 c = ((const u16x8*)S1)[j];
      u16x8 ov;
#pragma unroll
      for (int e = 0; e < 8; e++) ov[e] = f2bf((bf2f(a[e]) + bf2f(c[e])) * inv);
      ((u16x8*)yp)[j] = ov;
    }
  }
}

// ---------- residual + LayerNorm (scale only) ----------
__global__ __launch_bounds__(256) void ln_kernel(const float* __restrict__ y2,
                                                 const float* __restrict__ qin,
                                                 const float* __restrict__ lnw,
                                                 float* __restrict__ out) {
  const int row = blockIdx.x, t = threadIdx.x;
  const float4* Y = (const float4*)(y2 + (size_t)row * EMB);
  const float4* Qv = (const float4*)(qin + (size_t)row * EMB);
  float4 a = Y[t], b = Qv[t];
  float4 x0, x1;
  x0.x = a.x + b.x; x0.y = a.y + b.y; x0.z = a.z + b.z; x0.w = a.w + b.w;
  a = Y[t + 256]; b = Qv[t + 256];
  x1.x = a.x + b.x; x1.y = a.y + b.y; x1.z = a.z + b.z; x1.w = a.w + b.w;
  float s = x0.x + x0.y + x0.z + x0.w + x1.x + x1.y + x1.z + x1.w;
  float s2 = x0.x * x0.x + x0.y * x0.y + x0.z * x0.z + x0.w * x0.w +
             x1.x * x1.x + x1.y * x1.y + x1.z * x1.z + x1.w * x1.w;
#pragma unroll
  for (int d = 1; d < 64; d <<= 1) {
    s += __shfl_xor(s, d, 64);
    s2 += __shfl_xor(s2, d, 64);
  }
  __shared__ float red[8];
  if ((t & 63) == 0) { red[(t >> 6) * 2] = s; red[(t >> 6) * 2 + 1] = s2; }
  __syncthreads();
  s = red[0] + red[2] + red[4] + red[6];
  s2 = red[1] + red[3] + red[5] + red[7];
  float mu = s * (1.0f / EMB);
  float var = s2 * (1.0f / EMB) - mu * mu;
  float r = rsqrtf(var + 1e-5f);
  float4 w0 = ((const float4*)lnw)[t], w1 = ((const float4*)lnw)[t + 256];
  float4 o0, o1;
  o0.x = (x0.x - mu) * r * w0.x; o0.y = (x0.y - mu) * r * w0.y;
  o0.z = (x0.z - mu) * r * w0.z; o0.w = (x0.w - mu) * r * w0.w;
  o1.x = (x1.x - mu) * r * w1.x; o1.y = (x1.y - mu) * r * w1.y;
  o1.z = (x1.z - mu) * r * w1.z; o1.w = (x1.w - mu) * r * w1.w;
  ((float4*)(out + (size_t)row * EMB))[t] = o0;
  ((float4*)(out + (size_t)row * EMB))[t + 256] = o1;
}

// ---------- launch ----------
extern "C" void kernel_launch(void* const* d_in, const int* in_sizes, int n_in,
                              void* d_out, int out_size, void* d_ws, size_t ws_size,
                              hipStream_t stream) {
  const float* q = (const float*)d_in[0];
  const float* k = (const float*)d_in[1];
  const float* v = (const float*)d_in[2];
  const float* Wq = (const float*)d_in[3];
  const float* Wk = (const float*)d_in[4];
  const float* Wv = (const float*)d_in[5];
  const float* Wo = (const float*)d_in[6];
  const float* lnw = (const float*)d_in[7];
  float* out = (float*)d_out;
  char* ws = (char*)d_ws;

  const size_t WB = (size_t)EMB * EMB * 2;       // 8 MB  (bf16 weight)
  const size_t XB = (size_t)TSEQ * EMB * 2;      // 16 MB (bf16 activation)
  unsigned short* Wq_b = (unsigned short*)(ws + 0 * WB);
  unsigned short* Wk_b = (unsigned short*)(ws + 1 * WB);
  unsigned short* Wv_b = (unsigned short*)(ws + 2 * WB);
  unsigned short* Wo_b = (unsigned short*)(ws + 3 * WB);
  unsigned short* qb   = (unsigned short*)(ws + 4 * WB);
  unsigned short* kb   = (unsigned short*)(ws + 4 * WB + XB);
  unsigned short* vb   = (unsigned short*)(ws + 4 * WB + 2 * XB);
  unsigned short* Qb   = (unsigned short*)(ws + 4 * WB + 3 * XB);
  unsigned short* Kb   = (unsigned short*)(ws + 4 * WB + 4 * XB);
  unsigned short* Vtb  = (unsigned short*)(ws + 4 * WB + 5 * XB);
  unsigned short* yb   = qb;                         // reuse (qb dead after QKV proj)
  // slots/lbuf live in the dead kb/vb region [48,80) MB during attn+merge
  unsigned short* slots = (unsigned short*)(ws + 4 * WB + XB);                       // 24 MB
  float* lbuf = (float*)(ws + 4 * WB + XB + (size_t)768 * 128 * 128 * 2);            // 393 KB
  float* y2 = (float*)(ws + 4 * WB + XB);            // fp32 gemm_o out (overwrites slots after merge)

  cvt_all<<<20480, 256, 0, stream>>>(q, k, v, Wq, Wk, Wv, Wo,
                                     qb, kb, vb, Wq_b, Wk_b, Wv_b, Wo_b);

  gemm_qkv<<<1536, 256, 0, stream>>>(qb, kb, vb, Wq_b, Wk_b, Wv_b, Qb, Kb, Vtb);

  attn_kernel<<<512, 256, 0, stream>>>(Qb, Kb, Vtb, slots, lbuf);

  merge_kernel<<<512, 256, 0, stream>>>(slots, lbuf, yb);

  gemm_o<<<dim3(16, 32), 256, 0, stream>>>(yb, Wo_b, y2);

  ln_kernel<<<TSEQ, 256, 0, stream>>>(y2, q, lnw, out);
}